// Round 9
// baseline (13737.344 us; speedup 1.0000x reference)
//
#include <hip/hip_runtime.h>
#include <cstdint>
#include <cstddef>

// Attention_41231686042092: ViT attention + softmax sparsification (per-(b,h)
// exact median threshold via 3-level radix select on f32 bit patterns) +
// diag-based token pruning + projection.
//
// Round-9:
//  * Selection passes (attn_stats, hist 0/1/2): K staged in two d-halves ->
//    LDS 52->36KB / 68->52KB -> +1 block/CU occupancy. The fmaf chain order
//    is IDENTICAL to round-8 (same ascending-d fma4 sequence) -> bit-exact.
//  * av -> bf16 MFMA (2-way hi/lo split, 3 terms, ~1e-4 rel). Safe: av is
//    downstream of ranking; sigma-boundary mask toggles are ~0.002 on a
//    0.108 threshold. K/V pre-converted to bf16 planes (V transposed) by
//    cvt_planes so av has zero conversion cost. ws-guarded with f32 fallback.
//  * qkv (f32 64x128/4x8, 526us) and proj_mfma unchanged from round-8.

namespace {
constexpr int B_  = 16;
constexpr int N_  = 577;
constexpr int C_  = 768;
constexpr int H_  = 12;
constexpr int HD_ = 64;
constexpr int BH_ = B_ * H_;            // 192
constexpr int KK_ = N_ - 57;            // 520 kept tokens
constexpr unsigned KIDX_ = 166464u;     // int(N*N*0.5), 0-based desc rank
constexpr int M1_ = B_ * N_;            // 9232
constexpr int M2_ = B_ * KK_;           // 8320
constexpr int NPAD_ = 640;              // padded n for bf16 planes
}

typedef __attribute__((ext_vector_type(8))) short bfx8;
typedef __attribute__((ext_vector_type(4))) float fx4;

__device__ __forceinline__ void fma4(const float4& a, const float4& b, float& acc) {
  acc = __builtin_fmaf(a.x, b.x, acc);
  acc = __builtin_fmaf(a.y, b.y, acc);
  acc = __builtin_fmaf(a.z, b.z, acc);
  acc = __builtin_fmaf(a.w, b.w, acc);
}

__device__ __forceinline__ unsigned short f2bf(float x) {
  unsigned u = __float_as_uint(x);
  unsigned r = u + 0x7FFFu + ((u >> 16) & 1u);
  return (unsigned short)(r >> 16);
}
__device__ __forceinline__ float bf2f(unsigned short h) {
  return __uint_as_float(((unsigned)h) << 16);
}

// ---------------------------------------------------------------- QKV GEMM
// Round-4 version: 64x128 tile, 4x8 microtile, k-chunk 64 (measured 526us).
__global__ __launch_bounds__(256) void qkv_gemm(
    const float* __restrict__ X, const float* __restrict__ W,
    float* __restrict__ qb, float* __restrict__ kb, float* __restrict__ vb) {
  __shared__ __align__(16) float Xs[64][68];
  __shared__ __align__(16) float Ws2[128][68];
  const int m0 = blockIdx.x * 64;
  const int n0 = blockIdx.y * 128;
  const int t = threadIdx.x;
  const int tx = t & 15, ty = t >> 4;
  float acc[4][8] = {};
  for (int k0 = 0; k0 < 768; k0 += 64) {
    __syncthreads();
    {
      const int c = t & 15, r0 = t >> 4;
#pragma unroll
      for (int s = 0; s < 4; s++) {
        int r = r0 + 16 * s;
        int gm = m0 + r;
        float4 v = make_float4(0.f, 0.f, 0.f, 0.f);
        if (gm < M1_) v = *(const float4*)&X[(size_t)gm * 768 + k0 + 4 * c];
        *(float4*)&Xs[r][4 * c] = v;
      }
#pragma unroll
      for (int s = 0; s < 8; s++) {
        int r = r0 + 16 * s;
        float4 v = *(const float4*)&W[(size_t)(n0 + r) * 768 + k0 + 4 * c];
        *(float4*)&Ws2[r][4 * c] = v;
      }
    }
    __syncthreads();
#pragma unroll 2
    for (int d4 = 0; d4 < 16; d4++) {
      float4 a4[4], b4[8];
#pragma unroll
      for (int i = 0; i < 4; i++) a4[i] = *(const float4*)&Xs[tx + 16 * i][4 * d4];
#pragma unroll
      for (int j = 0; j < 8; j++) b4[j] = *(const float4*)&Ws2[ty + 16 * j][4 * d4];
#pragma unroll
      for (int i = 0; i < 4; i++)
#pragma unroll
        for (int j = 0; j < 8; j++) fma4(a4[i], b4[j], acc[i][j]);
    }
  }
  for (int i = 0; i < 4; i++) {
    int gm = m0 + tx + 16 * i;
    if (gm >= M1_) continue;
    int b = gm / N_, n = gm % N_;
    for (int j = 0; j < 8; j++) {
      int gn = n0 + ty + 16 * j;
      int which = gn / C_, rem = gn % C_;
      int h = rem >> 6, d = rem & 63;
      float* dst = (which == 0) ? qb : (which == 1) ? kb : vb;
      dst[(((size_t)(b * H_ + h)) * N_ + n) * HD_ + d] = acc[i][j];
    }
  }
}

// ------------------------------------- K/V -> bf16 planes (for av_mfma)
// khi/klo: [bh][NPAD][64] (n rows >= N_ zeroed). vthi/vtlo: [bh][64][NPAD]
// (transposed; n cols >= N_ zeroed).
__global__ __launch_bounds__(256) void cvt_planes(
    const float* __restrict__ kb, const float* __restrict__ vb,
    unsigned short* __restrict__ khi, unsigned short* __restrict__ klo,
    unsigned short* __restrict__ vthi, unsigned short* __restrict__ vtlo) {
  __shared__ __align__(16) float Vl[64][68];
  const int bh = blockIdx.x;
  const int n0 = blockIdx.y * 64;
  const int t = threadIdx.x;
  const int nl = t >> 2, c16 = (t & 3) * 16;
  const int gn = n0 + nl;
  {  // K planes (always write; zero beyond N_)
    short hh[16], ll[16];
    if (gn < N_) {
      const float* src = &kb[((size_t)bh * N_ + gn) * HD_ + c16];
#pragma unroll
      for (int u = 0; u < 16; u += 4) {
        float4 v = *(const float4*)&src[u];
        const float* vp = (const float*)&v;
#pragma unroll
        for (int e = 0; e < 4; e++) {
          unsigned short h = f2bf(vp[e]);
          hh[u + e] = (short)h;
          ll[u + e] = (short)f2bf(vp[e] - bf2f(h));
        }
      }
    } else {
#pragma unroll
      for (int e = 0; e < 16; e++) { hh[e] = 0; ll[e] = 0; }
    }
    unsigned short* kh = &khi[((size_t)bh * NPAD_ + gn) * HD_ + c16];
    unsigned short* kl = &klo[((size_t)bh * NPAD_ + gn) * HD_ + c16];
    *(bfx8*)&kh[0] = *(bfx8*)&hh[0]; *(bfx8*)&kh[8] = *(bfx8*)&hh[8];
    *(bfx8*)&kl[0] = *(bfx8*)&ll[0]; *(bfx8*)&kl[8] = *(bfx8*)&ll[8];
  }
  {  // V: stage f32 tile, then write transposed planes
    float4 z = make_float4(0.f, 0.f, 0.f, 0.f);
#pragma unroll
    for (int u = 0; u < 16; u += 4) {
      float4 v = z;
      if (gn < N_) v = *(const float4*)&vb[((size_t)bh * N_ + gn) * HD_ + c16 + u];
      *(float4*)&Vl[nl][c16 + u] = v;
    }
    __syncthreads();
    const int d = t >> 2, m16 = (t & 3) * 16;
    short hh[16], ll[16];
#pragma unroll
    for (int e = 0; e < 16; e++) {
      float x = Vl[m16 + e][d];
      unsigned short h = f2bf(x);
      hh[e] = (short)h;
      ll[e] = (short)f2bf(x - bf2f(h));
    }
    unsigned short* vh = &vthi[((size_t)bh * HD_ + d) * NPAD_ + n0 + m16];
    unsigned short* vl = &vtlo[((size_t)bh * HD_ + d) * NPAD_ + n0 + m16];
    *(bfx8*)&vh[0] = *(bfx8*)&hh[0]; *(bfx8*)&vh[8] = *(bfx8*)&hh[8];
    *(bfx8*)&vl[0] = *(bfx8*)&ll[0]; *(bfx8*)&vl[8] = *(bfx8*)&ll[8];
  }
}

// -------------------------------------------------- stats (QK pass #1)
// d-halved K staging (LDS 36KB -> 4 blocks/CU). fma4 chain order identical
// to round-8 -> bit-exact logits.
__global__ __launch_bounds__(256) void attn_stats(
    const float* __restrict__ qb, const float* __restrict__ kb,
    float* __restrict__ rowmax_g, float* __restrict__ rowsum_g,
    float* __restrict__ ldiag) {
  __shared__ __align__(16) float Qs[64][68];
  __shared__ __align__(16) float Ksf[128][36];
  const int bh = blockIdx.x;
  const int q0 = blockIdx.y * 64;
  const int t = threadIdx.x;
  const int tx = t & 15, ty = t >> 4;
  {
    const int c = t & 15, r0 = t >> 4;
#pragma unroll
    for (int s = 0; s < 4; s++) {
      int r = r0 + 16 * s;
      int gq = q0 + r;
      float4 v = make_float4(0.f, 0.f, 0.f, 0.f);
      if (gq < N_) v = *(const float4*)&qb[((size_t)bh * N_ + gq) * HD_ + 4 * c];
      v.x *= 0.125f; v.y *= 0.125f; v.z *= 0.125f; v.w *= 0.125f;
      *(float4*)&Qs[r][4 * c] = v;
    }
  }
  float m[4], ss[4];
#pragma unroll
  for (int i = 0; i < 4; i++) { m[i] = -INFINITY; ss[i] = 0.f; }
  for (int n0 = 0; n0 < N_; n0 += 128) {
    float l[4][8];
#pragma unroll
    for (int i = 0; i < 4; i++)
#pragma unroll
      for (int j = 0; j < 8; j++) l[i][j] = 0.f;
#pragma unroll
    for (int half = 0; half < 2; half++) {
      __syncthreads();
      {
        const int c8 = t & 7, r0 = t >> 3;
#pragma unroll
        for (int s = 0; s < 4; s++) {
          int r = r0 + 32 * s;
          int gn = n0 + r;
          float4 v = make_float4(0.f, 0.f, 0.f, 0.f);
          if (gn < N_) v = *(const float4*)&kb[((size_t)bh * N_ + gn) * HD_ + 32 * half + 4 * c8];
          *(float4*)&Ksf[r][4 * c8] = v;
        }
      }
      __syncthreads();
#pragma unroll
      for (int d4 = 0; d4 < 8; d4++) {
        float4 a4[4], b4[8];
#pragma unroll
        for (int i = 0; i < 4; i++) a4[i] = *(const float4*)&Qs[tx + 16 * i][32 * half + 4 * d4];
#pragma unroll
        for (int j = 0; j < 8; j++) b4[j] = *(const float4*)&Ksf[ty + 16 * j][4 * d4];
#pragma unroll
        for (int i = 0; i < 4; i++)
#pragma unroll
          for (int j = 0; j < 8; j++) fma4(a4[i], b4[j], l[i][j]);
      }
    }
#pragma unroll
    for (int i = 0; i < 4; i++) {
      int gq = q0 + tx + 16 * i;
      float tmax = -INFINITY;
#pragma unroll
      for (int j = 0; j < 8; j++)
        if (n0 + ty + 16 * j < N_) tmax = fmaxf(tmax, l[i][j]);
      float mn = fmaxf(m[i], tmax);
      ss[i] *= expf(m[i] - mn);
#pragma unroll
      for (int j = 0; j < 8; j++) {
        int col = n0 + ty + 16 * j;
        if (col < N_) {
          ss[i] += expf(l[i][j] - mn);
          if (col == gq) ldiag[(size_t)bh * N_ + gq] = l[i][j];
        }
      }
      m[i] = mn;
    }
  }
  __syncthreads();
  float* Mred = &Ksf[0][0];   // overlay (Ksf dead): 64x16 each (needs 2048 <= 4608)
  float* Sred = &Ksf[0][0] + 1024;
#pragma unroll
  for (int i = 0; i < 4; i++) {
    int row = tx + 16 * i;
    Mred[row * 16 + ty] = m[i];
    Sred[row * 16 + ty] = ss[i];
  }
  __syncthreads();
  if (t < 64) {
    int gq = q0 + t;
    if (gq < N_) {
      float M = -INFINITY;
      for (int k = 0; k < 16; k++) M = fmaxf(M, Mred[t * 16 + k]);
      float S = 0.f;
      for (int k = 0; k < 16; k++) S += expf(Mred[t * 16 + k] - M) * Sred[t * 16 + k];
      rowmax_g[(size_t)bh * N_ + gq] = M;
      rowsum_g[(size_t)bh * N_ + gq] = S;
    }
  }
}

// ----------------------------------------- histogram passes (QK #2,#3,#4)
template <int MODE>
__global__ __launch_bounds__(256) void hist_pass(
    const float* __restrict__ qb, const float* __restrict__ kb,
    const float* __restrict__ rowmax_g, const float* __restrict__ rowsum_g,
    const unsigned* __restrict__ pfx_in, unsigned* __restrict__ hist_out) {
  constexpr int HB = (MODE == 2) ? 256 : 4096;
  __shared__ __align__(16) float Qs[64][68];
  __shared__ __align__(16) float Ksf[128][36];
  __shared__ unsigned hloc[HB];
  const int bh = blockIdx.x;
  const int q0 = blockIdx.y * 64;
  const int t = threadIdx.x;
  const int tx = t & 15, ty = t >> 4;
  for (int i = t; i < HB; i += 256) hloc[i] = 0u;
  const unsigned pf = (MODE == 0) ? 0u : pfx_in[bh];
  {
    const int c = t & 15, r0 = t >> 4;
#pragma unroll
    for (int s = 0; s < 4; s++) {
      int r = r0 + 16 * s;
      int gq = q0 + r;
      float4 v = make_float4(0.f, 0.f, 0.f, 0.f);
      if (gq < N_) v = *(const float4*)&qb[((size_t)bh * N_ + gq) * HD_ + 4 * c];
      v.x *= 0.125f; v.y *= 0.125f; v.z *= 0.125f; v.w *= 0.125f;
      *(float4*)&Qs[r][4 * c] = v;
    }
  }
  float M[4], inv[4];
#pragma unroll
  for (int i = 0; i < 4; i++) {
    int gq = q0 + tx + 16 * i;
    if (gq < N_) {
      M[i] = rowmax_g[(size_t)bh * N_ + gq];
      inv[i] = 1.f / rowsum_g[(size_t)bh * N_ + gq];
    } else { M[i] = 0.f; inv[i] = 0.f; }
  }
  for (int n0 = 0; n0 < N_; n0 += 128) {
    float l[4][8];
#pragma unroll
    for (int i = 0; i < 4; i++)
#pragma unroll
      for (int j = 0; j < 8; j++) l[i][j] = 0.f;
#pragma unroll
    for (int half = 0; half < 2; half++) {
      __syncthreads();
      {
        const int c8 = t & 7, r0 = t >> 3;
#pragma unroll
        for (int s = 0; s < 4; s++) {
          int r = r0 + 32 * s;
          int gn = n0 + r;
          float4 v = make_float4(0.f, 0.f, 0.f, 0.f);
          if (gn < N_) v = *(const float4*)&kb[((size_t)bh * N_ + gn) * HD_ + 32 * half + 4 * c8];
          *(float4*)&Ksf[r][4 * c8] = v;
        }
      }
      __syncthreads();
#pragma unroll
      for (int d4 = 0; d4 < 8; d4++) {
        float4 a4[4], b4[8];
#pragma unroll
        for (int i = 0; i < 4; i++) a4[i] = *(const float4*)&Qs[tx + 16 * i][32 * half + 4 * d4];
#pragma unroll
        for (int j = 0; j < 8; j++) b4[j] = *(const float4*)&Ksf[ty + 16 * j][4 * d4];
#pragma unroll
        for (int i = 0; i < 4; i++)
#pragma unroll
          for (int j = 0; j < 8; j++) fma4(a4[i], b4[j], l[i][j]);
      }
    }
#pragma unroll
    for (int i = 0; i < 4; i++) {
      int gq = q0 + tx + 16 * i;
#pragma unroll
      for (int j = 0; j < 8; j++) {
        bool valid = (gq < N_) && (n0 + ty + 16 * j < N_);
        if (MODE == 0) {
          unsigned bin = 0xFFFFu;
          if (valid) {
            float e = expf(l[i][j] - M[i]);
            float v = e * inv[i];
            bin = __float_as_uint(v) >> 20;
          }
          unsigned lead = (unsigned)__builtin_amdgcn_readfirstlane((int)bin);
          unsigned long long mm = __ballot(bin == lead);
          if (bin == lead) {
            if (lead != 0xFFFFu && (t & 63) == (__ffsll((unsigned long long)mm) - 1))
              atomicAdd(&hloc[lead], (unsigned)__popcll(mm));
          } else if (bin != 0xFFFFu) {
            atomicAdd(&hloc[bin], 1u);
          }
        } else if (valid) {
          float e = expf(l[i][j] - M[i]);
          float v = e * inv[i];
          unsigned bits = __float_as_uint(v);
          if (MODE == 1) {
            if ((bits >> 20) == pf) atomicAdd(&hloc[(bits >> 8) & 0xFFFu], 1u);
          } else {
            if ((bits >> 8) == pf) atomicAdd(&hloc[bits & 0xFFu], 1u);
          }
        }
      }
    }
  }
  __syncthreads();
  for (int i = t; i < HB; i += 256)
    if (hloc[i]) atomicAdd(&hist_out[(size_t)bh * HB + i], hloc[i]);
}

// ------------------------------------------------------ radix-select levels
__global__ __launch_bounds__(64) void select_level(
    const unsigned* __restrict__ hist, int nbins,
    const unsigned* __restrict__ krem_in, const unsigned* __restrict__ pfx_in,
    unsigned* __restrict__ krem_out, unsigned* __restrict__ pfx_out, int shift) {
  const int bh = blockIdx.x;
  const int l = threadIdx.x;
  const int seg = nbins / 64;
  const unsigned krem = krem_in ? krem_in[bh] : KIDX_;
  const unsigned* hb = hist + (size_t)bh * nbins;
  __shared__ unsigned ps[64];
  unsigned psum = 0;
  int hi = nbins - 1 - l * seg;
  for (int i = 0; i < seg; i++) psum += hb[hi - i];
  ps[l] = psum;
  __syncthreads();
  if (l == 0) {
    unsigned cum = 0, before = 0;
    int bin = 0;
    for (int j = 0; j < 64; j++) {
      if (cum + ps[j] > krem) {
        unsigned c = cum;
        int hj = nbins - 1 - j * seg;
        for (int i = 0; i < seg; i++) {
          unsigned cnt = hb[hj - i];
          if (c + cnt > krem) { bin = hj - i; before = c; break; }
          c += cnt;
        }
        break;
      }
      cum += ps[j];
    }
    unsigned p = pfx_in ? pfx_in[bh] : 0u;
    pfx_out[bh] = (p << shift) | (unsigned)bin;
    krem_out[bh] = krem - before;
  }
}

// ------------------------------------------------- token ranking (stable)
__global__ __launch_bounds__(576) void rank_kernel(
    const float* __restrict__ ldiag, const float* __restrict__ rowmax_g,
    const float* __restrict__ rowsum_g, const unsigned* __restrict__ sigbits,
    int* __restrict__ kept) {
  const int b = blockIdx.x;
  const int i = threadIdx.x;  // token i+1
  __shared__ float sc[576];
  float s = 0.f;
  for (int h = 0; h < H_; h++) {
    int bh = b * H_ + h;
    float l = ldiag[(size_t)bh * N_ + (i + 1)];
    float M = rowmax_g[(size_t)bh * N_ + (i + 1)];
    float inv = 1.f / rowsum_g[(size_t)bh * N_ + (i + 1)];
    float e = expf(l - M);
    float v = e * inv;   // bit-identical to hist computation
    float sg = __uint_as_float(sigbits[bh]);
    if (v >= sg) s = fmaxf(s, v);
  }
  sc[i] = s;
  __syncthreads();
  int r = 0;
  for (int j = 0; j < 576; j++) {
    float sj = sc[j];
    if (sj > s || (sj == s && j < i)) r++;
  }
  if (r < KK_ - 1) kept[b * KK_ + r + 1] = i + 1;
  if (i == 0) kept[b * KK_] = 0;
}

// ------------------------------------------------------ gather x_original
__global__ __launch_bounds__(256) void gather_x(
    const float* __restrict__ xo, const int* __restrict__ kept,
    float* __restrict__ out2) {
  const int bp = blockIdx.x;
  const int b = bp / KK_, p = bp % KK_;
  const int src = kept[b * KK_ + p];
  const float* s = xo + ((size_t)b * N_ + src) * C_;
  float* d = out2 + (size_t)bp * C_;
  for (int c = threadIdx.x; c < C_; c += 256) d[c] = s[c];
}

// --------------------------------- AV via bf16 MFMA (2-way split, 3 terms)
// 64 kept rows/block, 4 waves each owning a 16-row tile. Per 64-col chunk:
// QK (6 mfma x 4 col-tiles) -> P = mask(exp(l-M)*inv) split hi/lo into the
// K-plane LDS overlay -> PV (6 mfma x 4 d-tiles) into accPV.
__global__ __launch_bounds__(256) void av_mfma(
    const float* __restrict__ qb,
    const unsigned short* __restrict__ khi, const unsigned short* __restrict__ klo,
    const unsigned short* __restrict__ vthi, const unsigned short* __restrict__ vtlo,
    const int* __restrict__ kept, const float* __restrict__ rowmax_g,
    const float* __restrict__ rowsum_g, const unsigned* __restrict__ sigbits,
    float* __restrict__ out1) {
  __shared__ __align__(16) unsigned short Qh[64][72], Ql[64][72];
  __shared__ __align__(16) unsigned short Kh[64][72], Kl[64][72];  // -> P overlay
  __shared__ __align__(16) unsigned short Vh[64][72], Vlo[64][72]; // transposed V
  __shared__ int ridx[64];
  __shared__ float Ml[64], Il[64];
  const int bh = blockIdx.x;
  const int p0 = blockIdx.y * 64;
  const int b = bh / H_, h = bh % H_;
  const float sigma = __uint_as_float(sigbits[bh]);
  const int t = threadIdx.x;
  const int w = t >> 6, l = t & 63;
  const int lr = l & 15, lk8 = (l >> 4) * 8;
  if (t < 64) {
    int pp = p0 + t;
    int r = (pp < KK_) ? kept[b * KK_ + pp] : 0;
    ridx[t] = r;
    Ml[t] = rowmax_g[(size_t)bh * N_ + r];
    Il[t] = 1.f / rowsum_g[(size_t)bh * N_ + r];
  }
  __syncthreads();
  {  // stage Q planes (scaled by 0.125, exact pow2)
    const int qr = t >> 2, c16 = (t & 3) * 16;
    const float* src = &qb[((size_t)bh * N_ + ridx[qr]) * HD_ + c16];
    short hh[16], ll[16];
#pragma unroll
    for (int u = 0; u < 16; u += 4) {
      float4 v = *(const float4*)&src[u];
      const float* vp = (const float*)&v;
#pragma unroll
      for (int e = 0; e < 4; e++) {
        float x = vp[e] * 0.125f;
        unsigned short hb_ = f2bf(x);
        hh[u + e] = (short)hb_;
        ll[u + e] = (short)f2bf(x - bf2f(hb_));
      }
    }
    *(bfx8*)&Qh[qr][c16] = *(bfx8*)&hh[0]; *(bfx8*)&Qh[qr][c16 + 8] = *(bfx8*)&hh[8];
    *(bfx8*)&Ql[qr][c16] = *(bfx8*)&ll[0]; *(bfx8*)&Ql[qr][c16 + 8] = *(bfx8*)&ll[8];
  }
  fx4 accPV[4];
#pragma unroll
  for (int j = 0; j < 4; j++) accPV[j] = (fx4){0.f, 0.f, 0.f, 0.f};

  for (int n0 = 0; n0 < N_; n0 += 64) {
    __syncthreads();  // prev PV done (P overlays K)
    {  // stage K planes (rows n) and Vt planes (rows d)
      const int rr = t >> 2, c16 = (t & 3) * 16;
      const unsigned short* ksh = &khi[((size_t)bh * NPAD_ + n0 + rr) * HD_ + c16];
      const unsigned short* ksl = &klo[((size_t)bh * NPAD_ + n0 + rr) * HD_ + c16];
      *(bfx8*)&Kh[rr][c16] = *(const bfx8*)&ksh[0];
      *(bfx8*)&Kh[rr][c16 + 8] = *(const bfx8*)&ksh[8];
      *(bfx8*)&Kl[rr][c16] = *(const bfx8*)&ksl[0];
      *(bfx8*)&Kl[rr][c16 + 8] = *(const bfx8*)&ksl[8];
      const unsigned short* vsh = &vthi[((size_t)bh * HD_ + rr) * NPAD_ + n0 + c16];
      const unsigned short* vsl = &vtlo[((size_t)bh * HD_ + rr) * NPAD_ + n0 + c16];
      *(bfx8*)&Vh[rr][c16] = *(const bfx8*)&vsh[0];
      *(bfx8*)&Vh[rr][c16 + 8] = *(const bfx8*)&vsh[8];
      *(bfx8*)&Vlo[rr][c16] = *(const bfx8*)&vsl[0];
      *(bfx8*)&Vlo[rr][c16 + 8] = *(const bfx8*)&vsl[8];
    }
    __syncthreads();
    // QK: lacc[j] over 4 col-tiles
    bfx8 aH0 = *(const bfx8*)&Qh[16 * w + lr][lk8];
    bfx8 aH1 = *(const bfx8*)&Qh[16 * w + lr][32 + lk8];
    bfx8 aL0 = *(const bfx8*)&Ql[16 * w + lr][lk8];
    bfx8 aL1 = *(const bfx8*)&Ql[16 * w + lr][32 + lk8];
    fx4 lacc[4];
#pragma unroll
    for (int j = 0; j < 4; j++) {
      bfx8 bH0 = *(const bfx8*)&Kh[16 * j + lr][lk8];
      bfx8 bH1 = *(const bfx8*)&Kh[16 * j + lr][32 + lk8];
      bfx8 bL0 = *(const bfx8*)&Kl[16 * j + lr][lk8];
      bfx8 bL1 = *(const bfx8*)&Kl[16 * j + lr][32 + lk8];
      fx4 c = (fx4){0.f, 0.f, 0.f, 0.f};
      c = __builtin_amdgcn_mfma_f32_16x16x32_bf16(aH0, bH0, c, 0, 0, 0);
      c = __builtin_amdgcn_mfma_f32_16x16x32_bf16(aH1, bH1, c, 0, 0, 0);
      c = __builtin_amdgcn_mfma_f32_16x16x32_bf16(aH0, bL0, c, 0, 0, 0);
      c = __builtin_amdgcn_mfma_f32_16x16x32_bf16(aH1, bL1, c, 0, 0, 0);
      c = __builtin_amdgcn_mfma_f32_16x16x32_bf16(aL0, bH0, c, 0, 0, 0);
      c = __builtin_amdgcn_mfma_f32_16x16x32_bf16(aL1, bH1, c, 0, 0, 0);
      lacc[j] = c;
    }
    __syncthreads();  // all K reads done -> safe to overlay P
#pragma unroll
    for (int j = 0; j < 4; j++) {
#pragma unroll
      for (int r = 0; r < 4; r++) {
        int rr = 16 * w + (l >> 4) * 4 + r;
        int cc = 16 * j + lr;
        int gn = n0 + cc;
        float P = 0.f;
        if (gn < N_) {
          float e = expf(lacc[j][r] - Ml[rr]);
          float v = e * Il[rr];
          P = (v >= sigma) ? v : 0.f;
        }
        unsigned short ph = f2bf(P);
        Kh[rr][cc] = ph;
        Kl[rr][cc] = f2bf(P - bf2f(ph));
      }
    }
    __syncthreads();
    // PV
    bfx8 pH0 = *(const bfx8*)&Kh[16 * w + lr][lk8];
    bfx8 pH1 = *(const bfx8*)&Kh[16 * w + lr][32 + lk8];
    bfx8 pL0 = *(const bfx8*)&Kl[16 * w + lr][lk8];
    bfx8 pL1 = *(const bfx8*)&Kl[16 * w + lr][32 + lk8];
#pragma unroll
    for (int jd = 0; jd < 4; jd++) {
      bfx8 vH0 = *(const bfx8*)&Vh[16 * jd + lr][lk8];
      bfx8 vH1 = *(const bfx8*)&Vh[16 * jd + lr][32 + lk8];
      bfx8 vL0 = *(const bfx8*)&Vlo[16 * jd + lr][lk8];
      bfx8 vL1 = *(const bfx8*)&Vlo[16 * jd + lr][32 + lk8];
      fx4 c = accPV[jd];
      c = __builtin_amdgcn_mfma_f32_16x16x32_bf16(pH0, vH0, c, 0, 0, 0);
      c = __builtin_amdgcn_mfma_f32_16x16x32_bf16(pH1, vH1, c, 0, 0, 0);
      c = __builtin_amdgcn_mfma_f32_16x16x32_bf16(pH0, vL0, c, 0, 0, 0);
      c = __builtin_amdgcn_mfma_f32_16x16x32_bf16(pH1, vL1, c, 0, 0, 0);
      c = __builtin_amdgcn_mfma_f32_16x16x32_bf16(pL0, vH0, c, 0, 0, 0);
      c = __builtin_amdgcn_mfma_f32_16x16x32_bf16(pL1, vH1, c, 0, 0, 0);
      accPV[jd] = c;
    }
  }
#pragma unroll
  for (int jd = 0; jd < 4; jd++) {
#pragma unroll
    for (int r = 0; r < 4; r++) {
      int pp = p0 + 16 * w + (l >> 4) * 4 + r;
      if (pp < KK_)
        out1[((size_t)(b * KK_ + pp)) * C_ + h * HD_ + 16 * jd + lr] = accPV[jd][r];
    }
  }
}

// --------------------------------- AV fallback (f32, round-8 verified)
__global__ __launch_bounds__(256) void av_kernel(
    const float* __restrict__ qb, const float* __restrict__ kb,
    const float* __restrict__ vb, const int* __restrict__ kept,
    const float* __restrict__ rowmax_g, const float* __restrict__ rowsum_g,
    const unsigned* __restrict__ sigbits, float* __restrict__ out1) {
  __shared__ __align__(16) float Qs[64][68];
  __shared__ __align__(16) float Ksf[64][68];
  __shared__ __align__(16) float Vs[64][68];
  __shared__ int ridx[64];
  __shared__ float Ml[64], Il[64];
  const int bh = blockIdx.x;
  const int p0 = blockIdx.y * 64;
  const int b = bh / H_, h = bh % H_;
  const float sigma = __uint_as_float(sigbits[bh]);
  const int t = threadIdx.x;
  const int tx = t & 15, ty = t >> 4;
  if (t < 64) {
    int pp = p0 + t;
    int r = (pp < KK_) ? kept[b * KK_ + pp] : 0;
    ridx[t] = r;
    Ml[t] = rowmax_g[(size_t)bh * N_ + r];
    Il[t] = 1.f / rowsum_g[(size_t)bh * N_ + r];
  }
  __syncthreads();
  {
    const int c = t & 15, r0 = t >> 4;
#pragma unroll
    for (int s = 0; s < 4; s++) {
      int r = r0 + 16 * s;
      int gq = ridx[r];
      float4 v = *(const float4*)&qb[((size_t)bh * N_ + gq) * HD_ + 4 * c];
      v.x *= 0.125f; v.y *= 0.125f; v.z *= 0.125f; v.w *= 0.125f;
      *(float4*)&Qs[r][4 * c] = v;
    }
  }
  float M[4], inv[4];
#pragma unroll
  for (int i = 0; i < 4; i++) { int row = tx + 16 * i; M[i] = Ml[row]; inv[i] = Il[row]; }
  float acc[4][4] = {};
  for (int n0 = 0; n0 < N_; n0 += 64) {
    __syncthreads();
    {
      const int c = t & 15, r0 = t >> 4;
#pragma unroll
      for (int s = 0; s < 4; s++) {
        int r = r0 + 16 * s;
        int gn = n0 + r;
        float4 kv = make_float4(0.f, 0.f, 0.f, 0.f);
        float4 vv = make_float4(0.f, 0.f, 0.f, 0.f);
        if (gn < N_) {
          kv = *(const float4*)&kb[((size_t)bh * N_ + gn) * HD_ + 4 * c];
          vv = *(const float4*)&vb[((size_t)bh * N_ + gn) * HD_ + 4 * c];
        }
        *(float4*)&Ksf[r][4 * c] = kv;
        *(float4*)&Vs[r][4 * c] = vv;
      }
    }
    __syncthreads();
    float l[4][4];
#pragma unroll
    for (int i = 0; i < 4; i++)
#pragma unroll
      for (int j = 0; j < 4; j++) l[i][j] = 0.f;
#pragma unroll 4
    for (int d4 = 0; d4 < 16; d4++) {
      float4 a4[4], b4[4];
#pragma unroll
      for (int i = 0; i < 4; i++) a4[i] = *(const float4*)&Qs[tx + 16 * i][4 * d4];
#pragma unroll
      for (int j = 0; j < 4; j++) b4[j] = *(const float4*)&Ksf[4 * ty + j][4 * d4];
#pragma unroll
      for (int i = 0; i < 4; i++)
#pragma unroll
        for (int j = 0; j < 4; j++) fma4(a4[i], b4[j], l[i][j]);
    }
    __syncthreads();
#pragma unroll
    for (int i = 0; i < 4; i++) {
      float4 pv4;
      float* pp = (float*)&pv4;
#pragma unroll
      for (int j = 0; j < 4; j++) {
        float e = expf(l[i][j] - M[i]);
        float v = e * inv[i];
        pp[j] = (v >= sigma) ? v : 0.f;
      }
      *(float4*)&Ksf[tx + 16 * i][4 * ty] = pv4;
    }
    __syncthreads();
#pragma unroll 4
    for (int nb = 0; nb < 16; nb++) {
      float4 pa4[4];
#pragma unroll
      for (int i = 0; i < 4; i++) pa4[i] = *(const float4*)&Ksf[tx + 16 * i][4 * nb];
#pragma unroll
      for (int e = 0; e < 4; e++) {
        float4 vv4 = *(const float4*)&Vs[4 * nb + e][4 * ty];
#pragma unroll
        for (int i = 0; i < 4; i++) {
          float pvv = ((const float*)&pa4[i])[e];
          acc[i][0] = __builtin_fmaf(pvv, vv4.x, acc[i][0]);
          acc[i][1] = __builtin_fmaf(pvv, vv4.y, acc[i][1]);
          acc[i][2] = __builtin_fmaf(pvv, vv4.z, acc[i][2]);
          acc[i][3] = __builtin_fmaf(pvv, vv4.w, acc[i][3]);
        }
      }
    }
  }
#pragma unroll
  for (int i = 0; i < 4; i++) {
    int pp = p0 + tx + 16 * i;
    if (pp >= KK_) continue;
    float4 o = make_float4(acc[i][0], acc[i][1], acc[i][2], acc[i][3]);
    *(float4*)&out1[((size_t)(b * KK_ + pp)) * C_ + h * HD_ + 4 * ty] = o;
  }
}

// ------------------------------------------- proj GEMM via bf16 MFMA
__global__ __launch_bounds__(256) void proj_mfma(
    const float* __restrict__ Xi, const float* __restrict__ W,
    const float* __restrict__ bias, float* __restrict__ out) {
  __shared__ __align__(16) short XsH[128][40];
  __shared__ __align__(16) short XsL[128][40];
  __shared__ __align__(16) short WsH[128][40];
  __shared__ __align__(16) short WsL[128][40];
  const int m0 = blockIdx.x * 128;
  const int n0 = blockIdx.y * 128;
  const int t = threadIdx.x;
  const int w = t >> 6;
  const int l = t & 63;
  const int wm = (w & 1) * 64;
  const int wn = (w >> 1) * 64;
  const int srow = t >> 1;
  const int scol = (t & 1) * 16;

  fx4 acc[4][4];
#pragma unroll
  for (int i = 0; i < 4; i++)
#pragma unroll
    for (int j = 0; j < 4; j++) acc[i][j] = (fx4){0.f, 0.f, 0.f, 0.f};

  for (int k0 = 0; k0 < 768; k0 += 32) {
    __syncthreads();
    {
      const float* xsrc = &Xi[(size_t)(m0 + srow) * 768 + k0 + scol];
      const float* wsrc = &W[(size_t)(n0 + srow) * 768 + k0 + scol];
      short hx[16], lx[16], hw[16], lw[16];
#pragma unroll
      for (int u = 0; u < 16; u += 4) {
        float4 xv = *(const float4*)&xsrc[u];
        float4 wv = *(const float4*)&wsrc[u];
        const float* xp = (const float*)&xv;
        const float* wp = (const float*)&wv;
#pragma unroll
        for (int e = 0; e < 4; e++) {
          unsigned short h = f2bf(xp[e]);
          hx[u + e] = (short)h;
          lx[u + e] = (short)f2bf(xp[e] - bf2f(h));
          unsigned short g = f2bf(wp[e]);
          hw[u + e] = (short)g;
          lw[u + e] = (short)f2bf(wp[e] - bf2f(g));
        }
      }
      *(bfx8*)&XsH[srow][scol]     = *(bfx8*)&hx[0];
      *(bfx8*)&XsH[srow][scol + 8] = *(bfx8*)&hx[8];
      *(bfx8*)&XsL[srow][scol]     = *(bfx8*)&lx[0];
      *(bfx8*)&XsL[srow][scol + 8] = *(bfx8*)&lx[8];
      *(bfx8*)&WsH[srow][scol]     = *(bfx8*)&hw[0];
      *(bfx8*)&WsH[srow][scol + 8] = *(bfx8*)&hw[8];
      *(bfx8*)&WsL[srow][scol]     = *(bfx8*)&lw[0];
      *(bfx8*)&WsL[srow][scol + 8] = *(bfx8*)&lw[8];
    }
    __syncthreads();
    bfx8 aH[4], aL[4];
    const int ar = l & 15, ak = (l >> 4) * 8;
#pragma unroll
    for (int i = 0; i < 4; i++) {
      aH[i] = *(const bfx8*)&XsH[wm + 16 * i + ar][ak];
      aL[i] = *(const bfx8*)&XsL[wm + 16 * i + ar][ak];
    }
#pragma unroll
    for (int j = 0; j < 4; j++) {
      bfx8 bH = *(const bfx8*)&WsH[wn + 16 * j + ar][ak];
      bfx8 bL = *(const bfx8*)&WsL[wn + 16 * j + ar][ak];
#pragma unroll
      for (int i = 0; i < 4; i++) {
        acc[i][j] = __builtin_amdgcn_mfma_f32_16x16x32_bf16(aH[i], bH, acc[i][j], 0, 0, 0);
        acc[i][j] = __builtin_amdgcn_mfma_f32_16x16x32_bf16(aH[i], bL, acc[i][j], 0, 0, 0);
        acc[i][j] = __builtin_amdgcn_mfma_f32_16x16x32_bf16(aL[i], bH, acc[i][j], 0, 0, 0);
      }
    }
  }
  const int dc = l & 15, dr4 = (l >> 4) * 4;
#pragma unroll
  for (int j = 0; j < 4; j++) {
    int col = n0 + wn + 16 * j + dc;
    float bb = bias[col];
#pragma unroll
    for (int i = 0; i < 4; i++) {
#pragma unroll
      for (int r = 0; r < 4; r++) {
        int row = m0 + wm + 16 * i + dr4 + r;
        out[(size_t)row * C_ + col] = acc[i][j][r] + bb;
      }
    }
  }
}

// ---------------------------------------------------------------- launcher
extern "C" void kernel_launch(void* const* d_in, const int* in_sizes, int n_in,
                              void* d_out, int out_size, void* d_ws, size_t ws_size,
                              hipStream_t stream) {
  (void)in_sizes; (void)n_in; (void)out_size;
  const float* x    = (const float*)d_in[0];
  const float* xo   = (const float*)d_in[1];
  const float* qkvw = (const float*)d_in[2];
  const float* pw   = (const float*)d_in[3];
  const float* pb   = (const float*)d_in[4];

  char* ws = (char*)d_ws;
  size_t off = 0;
  auto alloc = [&](size_t bytes) -> char* {
    char* p = ws + off;
    off += (bytes + 255) & ~(size_t)255;
    return p;
  };
  const size_t szQ    = (size_t)BH_ * N_ * HD_ * 4;   // 28.4 MB
  const size_t szOut1 = (size_t)M2_ * C_ * 4;         // 25.6 MB
  const size_t szRow  = (size_t)BH_ * N_ * 4;
  const size_t szH12  = (size_t)BH_ * 4096 * 4;
  const size_t szH3   = (size_t)BH_ * 256 * 4;
  const size_t szPlane = (size_t)BH_ * NPAD_ * HD_ * 2;  // 15.7 MB each

  float* qb     = (float*)alloc(szQ);
  float* kb     = (float*)alloc(szQ);
  float* vb     = (float*)alloc(szQ);
  float* out1   = (float*)alloc(szOut1);
  float* ldiag  = (float*)alloc(szRow);
  float* rowmax = (float*)alloc(szRow);
  float* rowsum = (float*)alloc(szRow);
  unsigned* hist1 = (unsigned*)alloc(szH12);
  unsigned* hist2 = (unsigned*)alloc(szH12);
  unsigned* hist3 = (unsigned*)alloc(szH3);
  unsigned* pfx1  = (unsigned*)alloc(BH_ * 4);
  unsigned* krem1 = (unsigned*)alloc(BH_ * 4);
  unsigned* pfx2  = (unsigned*)alloc(BH_ * 4);
  unsigned* krem2 = (unsigned*)alloc(BH_ * 4);
  unsigned* sigb  = (unsigned*)alloc(BH_ * 4);
  unsigned* krem3 = (unsigned*)alloc(BH_ * 4);
  int* kept       = (int*)alloc((size_t)B_ * KK_ * 4);
  // bf16 planes last (optional, ws-guarded)
  unsigned short* khi  = (unsigned short*)alloc(szPlane);
  unsigned short* klo  = (unsigned short*)alloc(szPlane);
  unsigned short* vthi = (unsigned short*)alloc(szPlane);
  unsigned short* vtlo = (unsigned short*)alloc(szPlane);
  const bool use_mfma_av = (ws_size >= off);

  hipMemsetAsync(hist1, 0, szH12, stream);
  hipMemsetAsync(hist2, 0, szH12, stream);
  hipMemsetAsync(hist3, 0, szH3, stream);

  qkv_gemm<<<dim3(145, 18), 256, 0, stream>>>(x, qkvw, qb, kb, vb);
  if (use_mfma_av)
    cvt_planes<<<dim3(BH_, 10), 256, 0, stream>>>(kb, vb, khi, klo, vthi, vtlo);
  attn_stats<<<dim3(BH_, 10), 256, 0, stream>>>(qb, kb, rowmax, rowsum, ldiag);
  hist_pass<0><<<dim3(BH_, 10), 256, 0, stream>>>(qb, kb, rowmax, rowsum, nullptr, hist1);
  select_level<<<BH_, 64, 0, stream>>>(hist1, 4096, nullptr, nullptr, krem1, pfx1, 12);
  hist_pass<1><<<dim3(BH_, 10), 256, 0, stream>>>(qb, kb, rowmax, rowsum, pfx1, hist2);
  select_level<<<BH_, 64, 0, stream>>>(hist2, 4096, krem1, pfx1, krem2, pfx2, 12);
  hist_pass<2><<<dim3(BH_, 10), 256, 0, stream>>>(qb, kb, rowmax, rowsum, pfx2, hist3);
  select_level<<<BH_, 64, 0, stream>>>(hist3, 256, krem2, pfx2, krem3, sigb, 8);
  rank_kernel<<<B_, 576, 0, stream>>>(ldiag, rowmax, rowsum, sigb, kept);

  float* outp = (float*)d_out;
  gather_x<<<M2_, 256, 0, stream>>>(xo, kept, outp + (size_t)M2_ * C_);
  if (use_mfma_av)
    av_mfma<<<dim3(BH_, 9), 256, 0, stream>>>(qb, khi, klo, vthi, vtlo, kept,
                                              rowmax, rowsum, sigb, out1);
  else
    av_kernel<<<dim3(BH_, 9), 256, 0, stream>>>(qb, kb, vb, kept, rowmax, rowsum, sigb, out1);
  proj_mfma<<<dim3(65, 6), 256, 0, stream>>>(out1, pw, pb, outp);
}

// Round 10
// 1598.972 us; speedup vs baseline: 8.5914x; 8.5914x over previous
//
#include <hip/hip_runtime.h>
#include <cstdint>
#include <cstddef>

// Attention_41231686042092: ViT attention + softmax sparsification (per-(b,h)
// exact median threshold via 3-level radix select on f32 bit patterns) +
// diag-based token pruning + projection.
//
// Round-10: surgical revert of round-9's d-halved selection passes (they
// caused 256-VGPR scratch spill, 8.2GB traffic/dispatch, 22x regression).
// Selection passes = round-8 exact code. Keep: qkv f32 64x128/4x8 (526us),
// cvt_planes + av_mfma (numerically verified in round-9), proj_mfma.
// Every ranking-critical logit remains a single ascending-k fmaf chain.

namespace {
constexpr int B_  = 16;
constexpr int N_  = 577;
constexpr int C_  = 768;
constexpr int H_  = 12;
constexpr int HD_ = 64;
constexpr int BH_ = B_ * H_;            // 192
constexpr int KK_ = N_ - 57;            // 520 kept tokens
constexpr unsigned KIDX_ = 166464u;     // int(N*N*0.5), 0-based desc rank
constexpr int M1_ = B_ * N_;            // 9232
constexpr int M2_ = B_ * KK_;           // 8320
constexpr int NPAD_ = 640;              // padded n for bf16 planes
}

typedef __attribute__((ext_vector_type(8))) short bfx8;
typedef __attribute__((ext_vector_type(4))) float fx4;

__device__ __forceinline__ void fma4(const float4& a, const float4& b, float& acc) {
  acc = __builtin_fmaf(a.x, b.x, acc);
  acc = __builtin_fmaf(a.y, b.y, acc);
  acc = __builtin_fmaf(a.z, b.z, acc);
  acc = __builtin_fmaf(a.w, b.w, acc);
}

__device__ __forceinline__ unsigned short f2bf(float x) {
  unsigned u = __float_as_uint(x);
  unsigned r = u + 0x7FFFu + ((u >> 16) & 1u);
  return (unsigned short)(r >> 16);
}
__device__ __forceinline__ float bf2f(unsigned short h) {
  return __uint_as_float(((unsigned)h) << 16);
}

// ---------------------------------------------------------------- QKV GEMM
// Round-4 version: 64x128 tile, 4x8 microtile, k-chunk 64 (measured 526us).
__global__ __launch_bounds__(256) void qkv_gemm(
    const float* __restrict__ X, const float* __restrict__ W,
    float* __restrict__ qb, float* __restrict__ kb, float* __restrict__ vb) {
  __shared__ __align__(16) float Xs[64][68];
  __shared__ __align__(16) float Ws2[128][68];
  const int m0 = blockIdx.x * 64;
  const int n0 = blockIdx.y * 128;
  const int t = threadIdx.x;
  const int tx = t & 15, ty = t >> 4;
  float acc[4][8] = {};
  for (int k0 = 0; k0 < 768; k0 += 64) {
    __syncthreads();
    {
      const int c = t & 15, r0 = t >> 4;
#pragma unroll
      for (int s = 0; s < 4; s++) {
        int r = r0 + 16 * s;
        int gm = m0 + r;
        float4 v = make_float4(0.f, 0.f, 0.f, 0.f);
        if (gm < M1_) v = *(const float4*)&X[(size_t)gm * 768 + k0 + 4 * c];
        *(float4*)&Xs[r][4 * c] = v;
      }
#pragma unroll
      for (int s = 0; s < 8; s++) {
        int r = r0 + 16 * s;
        float4 v = *(const float4*)&W[(size_t)(n0 + r) * 768 + k0 + 4 * c];
        *(float4*)&Ws2[r][4 * c] = v;
      }
    }
    __syncthreads();
#pragma unroll 2
    for (int d4 = 0; d4 < 16; d4++) {
      float4 a4[4], b4[8];
#pragma unroll
      for (int i = 0; i < 4; i++) a4[i] = *(const float4*)&Xs[tx + 16 * i][4 * d4];
#pragma unroll
      for (int j = 0; j < 8; j++) b4[j] = *(const float4*)&Ws2[ty + 16 * j][4 * d4];
#pragma unroll
      for (int i = 0; i < 4; i++)
#pragma unroll
        for (int j = 0; j < 8; j++) fma4(a4[i], b4[j], acc[i][j]);
    }
  }
  for (int i = 0; i < 4; i++) {
    int gm = m0 + tx + 16 * i;
    if (gm >= M1_) continue;
    int b = gm / N_, n = gm % N_;
    for (int j = 0; j < 8; j++) {
      int gn = n0 + ty + 16 * j;
      int which = gn / C_, rem = gn % C_;
      int h = rem >> 6, d = rem & 63;
      float* dst = (which == 0) ? qb : (which == 1) ? kb : vb;
      dst[(((size_t)(b * H_ + h)) * N_ + n) * HD_ + d] = acc[i][j];
    }
  }
}

// ------------------------------------- K/V -> bf16 planes (for av_mfma)
__global__ __launch_bounds__(256) void cvt_planes(
    const float* __restrict__ kb, const float* __restrict__ vb,
    unsigned short* __restrict__ khi, unsigned short* __restrict__ klo,
    unsigned short* __restrict__ vthi, unsigned short* __restrict__ vtlo) {
  __shared__ __align__(16) float Vl[64][68];
  const int bh = blockIdx.x;
  const int n0 = blockIdx.y * 64;
  const int t = threadIdx.x;
  const int nl = t >> 2, c16 = (t & 3) * 16;
  const int gn = n0 + nl;
  {  // K planes (always write; zero beyond N_)
    short hh[16], ll[16];
    if (gn < N_) {
      const float* src = &kb[((size_t)bh * N_ + gn) * HD_ + c16];
#pragma unroll
      for (int u = 0; u < 16; u += 4) {
        float4 v = *(const float4*)&src[u];
        const float* vp = (const float*)&v;
#pragma unroll
        for (int e = 0; e < 4; e++) {
          unsigned short h = f2bf(vp[e]);
          hh[u + e] = (short)h;
          ll[u + e] = (short)f2bf(vp[e] - bf2f(h));
        }
      }
    } else {
#pragma unroll
      for (int e = 0; e < 16; e++) { hh[e] = 0; ll[e] = 0; }
    }
    unsigned short* kh = &khi[((size_t)bh * NPAD_ + gn) * HD_ + c16];
    unsigned short* kl = &klo[((size_t)bh * NPAD_ + gn) * HD_ + c16];
    *(bfx8*)&kh[0] = *(bfx8*)&hh[0]; *(bfx8*)&kh[8] = *(bfx8*)&hh[8];
    *(bfx8*)&kl[0] = *(bfx8*)&ll[0]; *(bfx8*)&kl[8] = *(bfx8*)&ll[8];
  }
  {  // V: stage f32 tile, then write transposed planes
    float4 z = make_float4(0.f, 0.f, 0.f, 0.f);
#pragma unroll
    for (int u = 0; u < 16; u += 4) {
      float4 v = z;
      if (gn < N_) v = *(const float4*)&vb[((size_t)bh * N_ + gn) * HD_ + c16 + u];
      *(float4*)&Vl[nl][c16 + u] = v;
    }
    __syncthreads();
    const int d = t >> 2, m16 = (t & 3) * 16;
    short hh[16], ll[16];
#pragma unroll
    for (int e = 0; e < 16; e++) {
      float x = Vl[m16 + e][d];
      unsigned short h = f2bf(x);
      hh[e] = (short)h;
      ll[e] = (short)f2bf(x - bf2f(h));
    }
    unsigned short* vh = &vthi[((size_t)bh * HD_ + d) * NPAD_ + n0 + m16];
    unsigned short* vl = &vtlo[((size_t)bh * HD_ + d) * NPAD_ + n0 + m16];
    *(bfx8*)&vh[0] = *(bfx8*)&hh[0]; *(bfx8*)&vh[8] = *(bfx8*)&hh[8];
    *(bfx8*)&vl[0] = *(bfx8*)&ll[0]; *(bfx8*)&vl[8] = *(bfx8*)&ll[8];
  }
}

// -------------------------------------------------- stats (QK pass #1)
// Round-8 exact code (68-col K staging; no spill).
__global__ __launch_bounds__(256) void attn_stats(
    const float* __restrict__ qb, const float* __restrict__ kb,
    float* __restrict__ rowmax_g, float* __restrict__ rowsum_g,
    float* __restrict__ ldiag) {
  __shared__ __align__(16) float Qs[64][68];
  __shared__ __align__(16) float Ksf[128][68];
  const int bh = blockIdx.x;
  const int q0 = blockIdx.y * 64;
  const int t = threadIdx.x;
  const int tx = t & 15, ty = t >> 4;
  {
    const int c = t & 15, r0 = t >> 4;
#pragma unroll
    for (int s = 0; s < 4; s++) {
      int r = r0 + 16 * s;
      int gq = q0 + r;
      float4 v = make_float4(0.f, 0.f, 0.f, 0.f);
      if (gq < N_) v = *(const float4*)&qb[((size_t)bh * N_ + gq) * HD_ + 4 * c];
      v.x *= 0.125f; v.y *= 0.125f; v.z *= 0.125f; v.w *= 0.125f;
      *(float4*)&Qs[r][4 * c] = v;
    }
  }
  float m[4], ss[4];
#pragma unroll
  for (int i = 0; i < 4; i++) { m[i] = -INFINITY; ss[i] = 0.f; }
  for (int n0 = 0; n0 < N_; n0 += 128) {
    __syncthreads();
    {
      const int c = t & 15, r0 = t >> 4;
#pragma unroll
      for (int s = 0; s < 8; s++) {
        int r = r0 + 16 * s;
        int gn = n0 + r;
        float4 v = make_float4(0.f, 0.f, 0.f, 0.f);
        if (gn < N_) v = *(const float4*)&kb[((size_t)bh * N_ + gn) * HD_ + 4 * c];
        *(float4*)&Ksf[r][4 * c] = v;
      }
    }
    __syncthreads();
    float l[4][8];
#pragma unroll
    for (int i = 0; i < 4; i++)
#pragma unroll
      for (int j = 0; j < 8; j++) l[i][j] = 0.f;
#pragma unroll 2
    for (int d4 = 0; d4 < 16; d4++) {
      float4 a4[4], b4[8];
#pragma unroll
      for (int i = 0; i < 4; i++) a4[i] = *(const float4*)&Qs[tx + 16 * i][4 * d4];
#pragma unroll
      for (int j = 0; j < 8; j++) b4[j] = *(const float4*)&Ksf[ty + 16 * j][4 * d4];
#pragma unroll
      for (int i = 0; i < 4; i++)
#pragma unroll
        for (int j = 0; j < 8; j++) fma4(a4[i], b4[j], l[i][j]);
    }
#pragma unroll
    for (int i = 0; i < 4; i++) {
      int gq = q0 + tx + 16 * i;
      float tmax = -INFINITY;
#pragma unroll
      for (int j = 0; j < 8; j++)
        if (n0 + ty + 16 * j < N_) tmax = fmaxf(tmax, l[i][j]);
      float mn = fmaxf(m[i], tmax);
      ss[i] *= expf(m[i] - mn);
#pragma unroll
      for (int j = 0; j < 8; j++) {
        int col = n0 + ty + 16 * j;
        if (col < N_) {
          ss[i] += expf(l[i][j] - mn);
          if (col == gq) ldiag[(size_t)bh * N_ + gq] = l[i][j];
        }
      }
      m[i] = mn;
    }
  }
  __syncthreads();
  float* Mred = &Ksf[0][0];   // overlay (Ksf dead): 64x16 each
  float* Sred = &Ksf[0][0] + 1024;
#pragma unroll
  for (int i = 0; i < 4; i++) {
    int row = tx + 16 * i;
    Mred[row * 16 + ty] = m[i];
    Sred[row * 16 + ty] = ss[i];
  }
  __syncthreads();
  if (t < 64) {
    int gq = q0 + t;
    if (gq < N_) {
      float M = -INFINITY;
      for (int k = 0; k < 16; k++) M = fmaxf(M, Mred[t * 16 + k]);
      float S = 0.f;
      for (int k = 0; k < 16; k++) S += expf(Mred[t * 16 + k] - M) * Sred[t * 16 + k];
      rowmax_g[(size_t)bh * N_ + gq] = M;
      rowsum_g[(size_t)bh * N_ + gq] = S;
    }
  }
}

// ----------------------------------------- histogram passes (QK #2,#3,#4)
// Round-8 exact code.
template <int MODE>
__global__ __launch_bounds__(256) void hist_pass(
    const float* __restrict__ qb, const float* __restrict__ kb,
    const float* __restrict__ rowmax_g, const float* __restrict__ rowsum_g,
    const unsigned* __restrict__ pfx_in, unsigned* __restrict__ hist_out) {
  constexpr int HB = (MODE == 2) ? 256 : 4096;
  __shared__ __align__(16) float Qs[64][68];
  __shared__ __align__(16) float Ksf[128][68];
  __shared__ unsigned hloc[HB];
  const int bh = blockIdx.x;
  const int q0 = blockIdx.y * 64;
  const int t = threadIdx.x;
  const int tx = t & 15, ty = t >> 4;
  for (int i = t; i < HB; i += 256) hloc[i] = 0u;
  const unsigned pf = (MODE == 0) ? 0u : pfx_in[bh];
  {
    const int c = t & 15, r0 = t >> 4;
#pragma unroll
    for (int s = 0; s < 4; s++) {
      int r = r0 + 16 * s;
      int gq = q0 + r;
      float4 v = make_float4(0.f, 0.f, 0.f, 0.f);
      if (gq < N_) v = *(const float4*)&qb[((size_t)bh * N_ + gq) * HD_ + 4 * c];
      v.x *= 0.125f; v.y *= 0.125f; v.z *= 0.125f; v.w *= 0.125f;
      *(float4*)&Qs[r][4 * c] = v;
    }
  }
  float M[4], inv[4];
#pragma unroll
  for (int i = 0; i < 4; i++) {
    int gq = q0 + tx + 16 * i;
    if (gq < N_) {
      M[i] = rowmax_g[(size_t)bh * N_ + gq];
      inv[i] = 1.f / rowsum_g[(size_t)bh * N_ + gq];
    } else { M[i] = 0.f; inv[i] = 0.f; }
  }
  for (int n0 = 0; n0 < N_; n0 += 128) {
    __syncthreads();
    {
      const int c = t & 15, r0 = t >> 4;
#pragma unroll
      for (int s = 0; s < 8; s++) {
        int r = r0 + 16 * s;
        int gn = n0 + r;
        float4 v = make_float4(0.f, 0.f, 0.f, 0.f);
        if (gn < N_) v = *(const float4*)&kb[((size_t)bh * N_ + gn) * HD_ + 4 * c];
        *(float4*)&Ksf[r][4 * c] = v;
      }
    }
    __syncthreads();
    float l[4][8];
#pragma unroll
    for (int i = 0; i < 4; i++)
#pragma unroll
      for (int j = 0; j < 8; j++) l[i][j] = 0.f;
#pragma unroll 2
    for (int d4 = 0; d4 < 16; d4++) {
      float4 a4[4], b4[8];
#pragma unroll
      for (int i = 0; i < 4; i++) a4[i] = *(const float4*)&Qs[tx + 16 * i][4 * d4];
#pragma unroll
      for (int j = 0; j < 8; j++) b4[j] = *(const float4*)&Ksf[ty + 16 * j][4 * d4];
#pragma unroll
      for (int i = 0; i < 4; i++)
#pragma unroll
        for (int j = 0; j < 8; j++) fma4(a4[i], b4[j], l[i][j]);
    }
#pragma unroll
    for (int i = 0; i < 4; i++) {
      int gq = q0 + tx + 16 * i;
#pragma unroll
      for (int j = 0; j < 8; j++) {
        bool valid = (gq < N_) && (n0 + ty + 16 * j < N_);
        if (MODE == 0) {
          unsigned bin = 0xFFFFu;
          if (valid) {
            float e = expf(l[i][j] - M[i]);
            float v = e * inv[i];
            bin = __float_as_uint(v) >> 20;
          }
          unsigned lead = (unsigned)__builtin_amdgcn_readfirstlane((int)bin);
          unsigned long long mm = __ballot(bin == lead);
          if (bin == lead) {
            if (lead != 0xFFFFu && (t & 63) == (__ffsll((unsigned long long)mm) - 1))
              atomicAdd(&hloc[lead], (unsigned)__popcll(mm));
          } else if (bin != 0xFFFFu) {
            atomicAdd(&hloc[bin], 1u);
          }
        } else if (valid) {
          float e = expf(l[i][j] - M[i]);
          float v = e * inv[i];
          unsigned bits = __float_as_uint(v);
          if (MODE == 1) {
            if ((bits >> 20) == pf) atomicAdd(&hloc[(bits >> 8) & 0xFFFu], 1u);
          } else {
            if ((bits >> 8) == pf) atomicAdd(&hloc[bits & 0xFFu], 1u);
          }
        }
      }
    }
  }
  __syncthreads();
  for (int i = t; i < HB; i += 256)
    if (hloc[i]) atomicAdd(&hist_out[(size_t)bh * HB + i], hloc[i]);
}

// ------------------------------------------------------ radix-select levels
__global__ __launch_bounds__(64) void select_level(
    const unsigned* __restrict__ hist, int nbins,
    const unsigned* __restrict__ krem_in, const unsigned* __restrict__ pfx_in,
    unsigned* __restrict__ krem_out, unsigned* __restrict__ pfx_out, int shift) {
  const int bh = blockIdx.x;
  const int l = threadIdx.x;
  const int seg = nbins / 64;
  const unsigned krem = krem_in ? krem_in[bh] : KIDX_;
  const unsigned* hb = hist + (size_t)bh * nbins;
  __shared__ unsigned ps[64];
  unsigned psum = 0;
  int hi = nbins - 1 - l * seg;
  for (int i = 0; i < seg; i++) psum += hb[hi - i];
  ps[l] = psum;
  __syncthreads();
  if (l == 0) {
    unsigned cum = 0, before = 0;
    int bin = 0;
    for (int j = 0; j < 64; j++) {
      if (cum + ps[j] > krem) {
        unsigned c = cum;
        int hj = nbins - 1 - j * seg;
        for (int i = 0; i < seg; i++) {
          unsigned cnt = hb[hj - i];
          if (c + cnt > krem) { bin = hj - i; before = c; break; }
          c += cnt;
        }
        break;
      }
      cum += ps[j];
    }
    unsigned p = pfx_in ? pfx_in[bh] : 0u;
    pfx_out[bh] = (p << shift) | (unsigned)bin;
    krem_out[bh] = krem - before;
  }
}

// ------------------------------------------------- token ranking (stable)
__global__ __launch_bounds__(576) void rank_kernel(
    const float* __restrict__ ldiag, const float* __restrict__ rowmax_g,
    const float* __restrict__ rowsum_g, const unsigned* __restrict__ sigbits,
    int* __restrict__ kept) {
  const int b = blockIdx.x;
  const int i = threadIdx.x;  // token i+1
  __shared__ float sc[576];
  float s = 0.f;
  for (int h = 0; h < H_; h++) {
    int bh = b * H_ + h;
    float l = ldiag[(size_t)bh * N_ + (i + 1)];
    float M = rowmax_g[(size_t)bh * N_ + (i + 1)];
    float inv = 1.f / rowsum_g[(size_t)bh * N_ + (i + 1)];
    float e = expf(l - M);
    float v = e * inv;   // bit-identical to hist computation
    float sg = __uint_as_float(sigbits[bh]);
    if (v >= sg) s = fmaxf(s, v);
  }
  sc[i] = s;
  __syncthreads();
  int r = 0;
  for (int j = 0; j < 576; j++) {
    float sj = sc[j];
    if (sj > s || (sj == s && j < i)) r++;
  }
  if (r < KK_ - 1) kept[b * KK_ + r + 1] = i + 1;
  if (i == 0) kept[b * KK_] = 0;
}

// ------------------------------------------------------ gather x_original
__global__ __launch_bounds__(256) void gather_x(
    const float* __restrict__ xo, const int* __restrict__ kept,
    float* __restrict__ out2) {
  const int bp = blockIdx.x;
  const int b = bp / KK_, p = bp % KK_;
  const int src = kept[b * KK_ + p];
  const float* s = xo + ((size_t)b * N_ + src) * C_;
  float* d = out2 + (size_t)bp * C_;
  for (int c = threadIdx.x; c < C_; c += 256) d[c] = s[c];
}

// --------------------------------- AV via bf16 MFMA (verified round-9)
__global__ __launch_bounds__(256) void av_mfma(
    const float* __restrict__ qb,
    const unsigned short* __restrict__ khi, const unsigned short* __restrict__ klo,
    const unsigned short* __restrict__ vthi, const unsigned short* __restrict__ vtlo,
    const int* __restrict__ kept, const float* __restrict__ rowmax_g,
    const float* __restrict__ rowsum_g, const unsigned* __restrict__ sigbits,
    float* __restrict__ out1) {
  __shared__ __align__(16) unsigned short Qh[64][72], Ql[64][72];
  __shared__ __align__(16) unsigned short Kh[64][72], Kl[64][72];  // -> P overlay
  __shared__ __align__(16) unsigned short Vh[64][72], Vlo[64][72]; // transposed V
  __shared__ int ridx[64];
  __shared__ float Ml[64], Il[64];
  const int bh = blockIdx.x;
  const int p0 = blockIdx.y * 64;
  const int b = bh / H_, h = bh % H_;
  const float sigma = __uint_as_float(sigbits[bh]);
  const int t = threadIdx.x;
  const int w = t >> 6, l = t & 63;
  const int lr = l & 15, lk8 = (l >> 4) * 8;
  if (t < 64) {
    int pp = p0 + t;
    int r = (pp < KK_) ? kept[b * KK_ + pp] : 0;
    ridx[t] = r;
    Ml[t] = rowmax_g[(size_t)bh * N_ + r];
    Il[t] = 1.f / rowsum_g[(size_t)bh * N_ + r];
  }
  __syncthreads();
  {  // stage Q planes (scaled by 0.125, exact pow2)
    const int qr = t >> 2, c16 = (t & 3) * 16;
    const float* src = &qb[((size_t)bh * N_ + ridx[qr]) * HD_ + c16];
    short hh[16], ll[16];
#pragma unroll
    for (int u = 0; u < 16; u += 4) {
      float4 v = *(const float4*)&src[u];
      const float* vp = (const float*)&v;
#pragma unroll
      for (int e = 0; e < 4; e++) {
        float x = vp[e] * 0.125f;
        unsigned short hb_ = f2bf(x);
        hh[u + e] = (short)hb_;
        ll[u + e] = (short)f2bf(x - bf2f(hb_));
      }
    }
    *(bfx8*)&Qh[qr][c16] = *(bfx8*)&hh[0]; *(bfx8*)&Qh[qr][c16 + 8] = *(bfx8*)&hh[8];
    *(bfx8*)&Ql[qr][c16] = *(bfx8*)&ll[0]; *(bfx8*)&Ql[qr][c16 + 8] = *(bfx8*)&ll[8];
  }
  fx4 accPV[4];
#pragma unroll
  for (int j = 0; j < 4; j++) accPV[j] = (fx4){0.f, 0.f, 0.f, 0.f};

  for (int n0 = 0; n0 < N_; n0 += 64) {
    __syncthreads();  // prev PV done (P overlays K)
    {  // stage K planes (rows n) and Vt planes (rows d)
      const int rr = t >> 2, c16 = (t & 3) * 16;
      const unsigned short* ksh = &khi[((size_t)bh * NPAD_ + n0 + rr) * HD_ + c16];
      const unsigned short* ksl = &klo[((size_t)bh * NPAD_ + n0 + rr) * HD_ + c16];
      *(bfx8*)&Kh[rr][c16] = *(const bfx8*)&ksh[0];
      *(bfx8*)&Kh[rr][c16 + 8] = *(const bfx8*)&ksh[8];
      *(bfx8*)&Kl[rr][c16] = *(const bfx8*)&ksl[0];
      *(bfx8*)&Kl[rr][c16 + 8] = *(const bfx8*)&ksl[8];
      const unsigned short* vsh = &vthi[((size_t)bh * HD_ + rr) * NPAD_ + n0 + c16];
      const unsigned short* vsl = &vtlo[((size_t)bh * HD_ + rr) * NPAD_ + n0 + c16];
      *(bfx8*)&Vh[rr][c16] = *(const bfx8*)&vsh[0];
      *(bfx8*)&Vh[rr][c16 + 8] = *(const bfx8*)&vsh[8];
      *(bfx8*)&Vlo[rr][c16] = *(const bfx8*)&vsl[0];
      *(bfx8*)&Vlo[rr][c16 + 8] = *(const bfx8*)&vsl[8];
    }
    __syncthreads();
    // QK: lacc[j] over 4 col-tiles
    bfx8 aH0 = *(const bfx8*)&Qh[16 * w + lr][lk8];
    bfx8 aH1 = *(const bfx8*)&Qh[16 * w + lr][32 + lk8];
    bfx8 aL0 = *(const bfx8*)&Ql[16 * w + lr][lk8];
    bfx8 aL1 = *(const bfx8*)&Ql[16 * w + lr][32 + lk8];
    fx4 lacc[4];
#pragma unroll
    for (int j = 0; j < 4; j++) {
      bfx8 bH0 = *(const bfx8*)&Kh[16 * j + lr][lk8];
      bfx8 bH1 = *(const bfx8*)&Kh[16 * j + lr][32 + lk8];
      bfx8 bL0 = *(const bfx8*)&Kl[16 * j + lr][lk8];
      bfx8 bL1 = *(const bfx8*)&Kl[16 * j + lr][32 + lk8];
      fx4 c = (fx4){0.f, 0.f, 0.f, 0.f};
      c = __builtin_amdgcn_mfma_f32_16x16x32_bf16(aH0, bH0, c, 0, 0, 0);
      c = __builtin_amdgcn_mfma_f32_16x16x32_bf16(aH1, bH1, c, 0, 0, 0);
      c = __builtin_amdgcn_mfma_f32_16x16x32_bf16(aH0, bL0, c, 0, 0, 0);
      c = __builtin_amdgcn_mfma_f32_16x16x32_bf16(aH1, bL1, c, 0, 0, 0);
      c = __builtin_amdgcn_mfma_f32_16x16x32_bf16(aL0, bH0, c, 0, 0, 0);
      c = __builtin_amdgcn_mfma_f32_16x16x32_bf16(aL1, bH1, c, 0, 0, 0);
      lacc[j] = c;
    }
    __syncthreads();  // all K reads done -> safe to overlay P
#pragma unroll
    for (int j = 0; j < 4; j++) {
#pragma unroll
      for (int r = 0; r < 4; r++) {
        int rr = 16 * w + (l >> 4) * 4 + r;
        int cc = 16 * j + lr;
        int gn = n0 + cc;
        float P = 0.f;
        if (gn < N_) {
          float e = expf(lacc[j][r] - Ml[rr]);
          float v = e * Il[rr];
          P = (v >= sigma) ? v : 0.f;
        }
        unsigned short ph = f2bf(P);
        Kh[rr][cc] = ph;
        Kl[rr][cc] = f2bf(P - bf2f(ph));
      }
    }
    __syncthreads();
    // PV
    bfx8 pH0 = *(const bfx8*)&Kh[16 * w + lr][lk8];
    bfx8 pH1 = *(const bfx8*)&Kh[16 * w + lr][32 + lk8];
    bfx8 pL0 = *(const bfx8*)&Kl[16 * w + lr][lk8];
    bfx8 pL1 = *(const bfx8*)&Kl[16 * w + lr][32 + lk8];
#pragma unroll
    for (int jd = 0; jd < 4; jd++) {
      bfx8 vH0 = *(const bfx8*)&Vh[16 * jd + lr][lk8];
      bfx8 vH1 = *(const bfx8*)&Vh[16 * jd + lr][32 + lk8];
      bfx8 vL0 = *(const bfx8*)&Vlo[16 * jd + lr][lk8];
      bfx8 vL1 = *(const bfx8*)&Vlo[16 * jd + lr][32 + lk8];
      fx4 c = accPV[jd];
      c = __builtin_amdgcn_mfma_f32_16x16x32_bf16(pH0, vH0, c, 0, 0, 0);
      c = __builtin_amdgcn_mfma_f32_16x16x32_bf16(pH1, vH1, c, 0, 0, 0);
      c = __builtin_amdgcn_mfma_f32_16x16x32_bf16(pH0, vL0, c, 0, 0, 0);
      c = __builtin_amdgcn_mfma_f32_16x16x32_bf16(pH1, vL1, c, 0, 0, 0);
      c = __builtin_amdgcn_mfma_f32_16x16x32_bf16(pL0, vH0, c, 0, 0, 0);
      c = __builtin_amdgcn_mfma_f32_16x16x32_bf16(pL1, vH1, c, 0, 0, 0);
      accPV[jd] = c;
    }
  }
#pragma unroll
  for (int jd = 0; jd < 4; jd++) {
#pragma unroll
    for (int r = 0; r < 4; r++) {
      int pp = p0 + 16 * w + (l >> 4) * 4 + r;
      if (pp < KK_)
        out1[((size_t)(b * KK_ + pp)) * C_ + h * HD_ + 16 * jd + lr] = accPV[jd][r];
    }
  }
}

// --------------------------------- AV fallback (f32, round-8 verified)
__global__ __launch_bounds__(256) void av_kernel(
    const float* __restrict__ qb, const float* __restrict__ kb,
    const float* __restrict__ vb, const int* __restrict__ kept,
    const float* __restrict__ rowmax_g, const float* __restrict__ rowsum_g,
    const unsigned* __restrict__ sigbits, float* __restrict__ out1) {
  __shared__ __align__(16) float Qs[64][68];
  __shared__ __align__(16) float Ksf[64][68];
  __shared__ __align__(16) float Vs[64][68];
  __shared__ int ridx[64];
  __shared__ float Ml[64], Il[64];
  const int bh = blockIdx.x;
  const int p0 = blockIdx.y * 64;
  const int b = bh / H_, h = bh % H_;
  const float sigma = __uint_as_float(sigbits[bh]);
  const int t = threadIdx.x;
  const int tx = t & 15, ty = t >> 4;
  if (t < 64) {
    int pp = p0 + t;
    int r = (pp < KK_) ? kept[b * KK_ + pp] : 0;
    ridx[t] = r;
    Ml[t] = rowmax_g[(size_t)bh * N_ + r];
    Il[t] = 1.f / rowsum_g[(size_t)bh * N_ + r];
  }
  __syncthreads();
  {
    const int c = t & 15, r0 = t >> 4;
#pragma unroll
    for (int s = 0; s < 4; s++) {
      int r = r0 + 16 * s;
      int gq = ridx[r];
      float4 v = *(const float4*)&qb[((size_t)bh * N_ + gq) * HD_ + 4 * c];
      v.x *= 0.125f; v.y *= 0.125f; v.z *= 0.125f; v.w *= 0.125f;
      *(float4*)&Qs[r][4 * c] = v;
    }
  }
  float M[4], inv[4];
#pragma unroll
  for (int i = 0; i < 4; i++) { int row = tx + 16 * i; M[i] = Ml[row]; inv[i] = Il[row]; }
  float acc[4][4] = {};
  for (int n0 = 0; n0 < N_; n0 += 64) {
    __syncthreads();
    {
      const int c = t & 15, r0 = t >> 4;
#pragma unroll
      for (int s = 0; s < 4; s++) {
        int r = r0 + 16 * s;
        int gn = n0 + r;
        float4 kv = make_float4(0.f, 0.f, 0.f, 0.f);
        float4 vv = make_float4(0.f, 0.f, 0.f, 0.f);
        if (gn < N_) {
          kv = *(const float4*)&kb[((size_t)bh * N_ + gn) * HD_ + 4 * c];
          vv = *(const float4*)&vb[((size_t)bh * N_ + gn) * HD_ + 4 * c];
        }
        *(float4*)&Ksf[r][4 * c] = kv;
        *(float4*)&Vs[r][4 * c] = vv;
      }
    }
    __syncthreads();
    float l[4][4];
#pragma unroll
    for (int i = 0; i < 4; i++)
#pragma unroll
      for (int j = 0; j < 4; j++) l[i][j] = 0.f;
#pragma unroll 4
    for (int d4 = 0; d4 < 16; d4++) {
      float4 a4[4], b4[4];
#pragma unroll
      for (int i = 0; i < 4; i++) a4[i] = *(const float4*)&Qs[tx + 16 * i][4 * d4];
#pragma unroll
      for (int j = 0; j < 4; j++) b4[j] = *(const float4*)&Ksf[4 * ty + j][4 * d4];
#pragma unroll
      for (int i = 0; i < 4; i++)
#pragma unroll
        for (int j = 0; j < 4; j++) fma4(a4[i], b4[j], l[i][j]);
    }
    __syncthreads();
#pragma unroll
    for (int i = 0; i < 4; i++) {
      float4 pv4;
      float* pp = (float*)&pv4;
#pragma unroll
      for (int j = 0; j < 4; j++) {
        float e = expf(l[i][j] - M[i]);
        float v = e * inv[i];
        pp[j] = (v >= sigma) ? v : 0.f;
      }
      *(float4*)&Ksf[tx + 16 * i][4 * ty] = pv4;
    }
    __syncthreads();
#pragma unroll 4
    for (int nb = 0; nb < 16; nb++) {
      float4 pa4[4];
#pragma unroll
      for (int i = 0; i < 4; i++) pa4[i] = *(const float4*)&Ksf[tx + 16 * i][4 * nb];
#pragma unroll
      for (int e = 0; e < 4; e++) {
        float4 vv4 = *(const float4*)&Vs[4 * nb + e][4 * ty];
#pragma unroll
        for (int i = 0; i < 4; i++) {
          float pvv = ((const float*)&pa4[i])[e];
          acc[i][0] = __builtin_fmaf(pvv, vv4.x, acc[i][0]);
          acc[i][1] = __builtin_fmaf(pvv, vv4.y, acc[i][1]);
          acc[i][2] = __builtin_fmaf(pvv, vv4.z, acc[i][2]);
          acc[i][3] = __builtin_fmaf(pvv, vv4.w, acc[i][3]);
        }
      }
    }
  }
#pragma unroll
  for (int i = 0; i < 4; i++) {
    int pp = p0 + tx + 16 * i;
    if (pp >= KK_) continue;
    float4 o = make_float4(acc[i][0], acc[i][1], acc[i][2], acc[i][3]);
    *(float4*)&out1[((size_t)(b * KK_ + pp)) * C_ + h * HD_ + 4 * ty] = o;
  }
}

// ------------------------------------------- proj GEMM via bf16 MFMA
__global__ __launch_bounds__(256) void proj_mfma(
    const float* __restrict__ Xi, const float* __restrict__ W,
    const float* __restrict__ bias, float* __restrict__ out) {
  __shared__ __align__(16) short XsH[128][40];
  __shared__ __align__(16) short XsL[128][40];
  __shared__ __align__(16) short WsH[128][40];
  __shared__ __align__(16) short WsL[128][40];
  const int m0 = blockIdx.x * 128;
  const int n0 = blockIdx.y * 128;
  const int t = threadIdx.x;
  const int w = t >> 6;
  const int l = t & 63;
  const int wm = (w & 1) * 64;
  const int wn = (w >> 1) * 64;
  const int srow = t >> 1;
  const int scol = (t & 1) * 16;

  fx4 acc[4][4];
#pragma unroll
  for (int i = 0; i < 4; i++)
#pragma unroll
    for (int j = 0; j < 4; j++) acc[i][j] = (fx4){0.f, 0.f, 0.f, 0.f};

  for (int k0 = 0; k0 < 768; k0 += 32) {
    __syncthreads();
    {
      const float* xsrc = &Xi[(size_t)(m0 + srow) * 768 + k0 + scol];
      const float* wsrc = &W[(size_t)(n0 + srow) * 768 + k0 + scol];
      short hx[16], lx[16], hw[16], lw[16];
#pragma unroll
      for (int u = 0; u < 16; u += 4) {
        float4 xv = *(const float4*)&xsrc[u];
        float4 wv = *(const float4*)&wsrc[u];
        const float* xp = (const float*)&xv;
        const float* wp = (const float*)&wv;
#pragma unroll
        for (int e = 0; e < 4; e++) {
          unsigned short h = f2bf(xp[e]);
          hx[u + e] = (short)h;
          lx[u + e] = (short)f2bf(xp[e] - bf2f(h));
          unsigned short g = f2bf(wp[e]);
          hw[u + e] = (short)g;
          lw[u + e] = (short)f2bf(wp[e] - bf2f(g));
        }
      }
      *(bfx8*)&XsH[srow][scol]     = *(bfx8*)&hx[0];
      *(bfx8*)&XsH[srow][scol + 8] = *(bfx8*)&hx[8];
      *(bfx8*)&XsL[srow][scol]     = *(bfx8*)&lx[0];
      *(bfx8*)&XsL[srow][scol + 8] = *(bfx8*)&lx[8];
      *(bfx8*)&WsH[srow][scol]     = *(bfx8*)&hw[0];
      *(bfx8*)&WsH[srow][scol + 8] = *(bfx8*)&hw[8];
      *(bfx8*)&WsL[srow][scol]     = *(bfx8*)&lw[0];
      *(bfx8*)&WsL[srow][scol + 8] = *(bfx8*)&lw[8];
    }
    __syncthreads();
    bfx8 aH[4], aL[4];
    const int ar = l & 15, ak = (l >> 4) * 8;
#pragma unroll
    for (int i = 0; i < 4; i++) {
      aH[i] = *(const bfx8*)&XsH[wm + 16 * i + ar][ak];
      aL[i] = *(const bfx8*)&XsL[wm + 16 * i + ar][ak];
    }
#pragma unroll
    for (int j = 0; j < 4; j++) {
      bfx8 bH = *(const bfx8*)&WsH[wn + 16 * j + ar][ak];
      bfx8 bL = *(const bfx8*)&WsL[wn + 16 * j + ar][ak];
#pragma unroll
      for (int i = 0; i < 4; i++) {
        acc[i][j] = __builtin_amdgcn_mfma_f32_16x16x32_bf16(aH[i], bH, acc[i][j], 0, 0, 0);
        acc[i][j] = __builtin_amdgcn_mfma_f32_16x16x32_bf16(aH[i], bL, acc[i][j], 0, 0, 0);
        acc[i][j] = __builtin_amdgcn_mfma_f32_16x16x32_bf16(aL[i], bH, acc[i][j], 0, 0, 0);
      }
    }
  }
  const int dc = l & 15, dr4 = (l >> 4) * 4;
#pragma unroll
  for (int j = 0; j < 4; j++) {
    int col = n0 + wn + 16 * j + dc;
    float bb = bias[col];
#pragma unroll
    for (int i = 0; i < 4; i++) {
#pragma unroll
      for (int r = 0; r < 4; r++) {
        int row = m0 + wm + 16 * i + dr4 + r;
        out[(size_t)row * C_ + col] = acc[i][j][r] + bb;
      }
    }
  }
}

// ---------------------------------------------------------------- launcher
extern "C" void kernel_launch(void* const* d_in, const int* in_sizes, int n_in,
                              void* d_out, int out_size, void* d_ws, size_t ws_size,
                              hipStream_t stream) {
  (void)in_sizes; (void)n_in; (void)out_size;
  const float* x    = (const float*)d_in[0];
  const float* xo   = (const float*)d_in[1];
  const float* qkvw = (const float*)d_in[2];
  const float* pw   = (const float*)d_in[3];
  const float* pb   = (const float*)d_in[4];

  char* ws = (char*)d_ws;
  size_t off = 0;
  auto alloc = [&](size_t bytes) -> char* {
    char* p = ws + off;
    off += (bytes + 255) & ~(size_t)255;
    return p;
  };
  const size_t szQ    = (size_t)BH_ * N_ * HD_ * 4;   // 28.4 MB
  const size_t szOut1 = (size_t)M2_ * C_ * 4;         // 25.6 MB
  const size_t szRow  = (size_t)BH_ * N_ * 4;
  const size_t szH12  = (size_t)BH_ * 4096 * 4;
  const size_t szH3   = (size_t)BH_ * 256 * 4;
  const size_t szPlane = (size_t)BH_ * NPAD_ * HD_ * 2;  // 15.7 MB each

  float* qb     = (float*)alloc(szQ);
  float* kb     = (float*)alloc(szQ);
  float* vb     = (float*)alloc(szQ);
  float* out1   = (float*)alloc(szOut1);
  float* ldiag  = (float*)alloc(szRow);
  float* rowmax = (float*)alloc(szRow);
  float* rowsum = (float*)alloc(szRow);
  unsigned* hist1 = (unsigned*)alloc(szH12);
  unsigned* hist2 = (unsigned*)alloc(szH12);
  unsigned* hist3 = (unsigned*)alloc(szH3);
  unsigned* pfx1  = (unsigned*)alloc(BH_ * 4);
  unsigned* krem1 = (unsigned*)alloc(BH_ * 4);
  unsigned* pfx2  = (unsigned*)alloc(BH_ * 4);
  unsigned* krem2 = (unsigned*)alloc(BH_ * 4);
  unsigned* sigb  = (unsigned*)alloc(BH_ * 4);
  unsigned* krem3 = (unsigned*)alloc(BH_ * 4);
  int* kept       = (int*)alloc((size_t)B_ * KK_ * 4);
  // bf16 planes last (optional, ws-guarded)
  unsigned short* khi  = (unsigned short*)alloc(szPlane);
  unsigned short* klo  = (unsigned short*)alloc(szPlane);
  unsigned short* vthi = (unsigned short*)alloc(szPlane);
  unsigned short* vtlo = (unsigned short*)alloc(szPlane);
  const bool use_mfma_av = (ws_size >= off);

  hipMemsetAsync(hist1, 0, szH12, stream);
  hipMemsetAsync(hist2, 0, szH12, stream);
  hipMemsetAsync(hist3, 0, szH3, stream);

  qkv_gemm<<<dim3(145, 18), 256, 0, stream>>>(x, qkvw, qb, kb, vb);
  if (use_mfma_av)
    cvt_planes<<<dim3(BH_, 10), 256, 0, stream>>>(kb, vb, khi, klo, vthi, vtlo);
  attn_stats<<<dim3(BH_, 10), 256, 0, stream>>>(qb, kb, rowmax, rowsum, ldiag);
  hist_pass<0><<<dim3(BH_, 10), 256, 0, stream>>>(qb, kb, rowmax, rowsum, nullptr, hist1);
  select_level<<<BH_, 64, 0, stream>>>(hist1, 4096, nullptr, nullptr, krem1, pfx1, 12);
  hist_pass<1><<<dim3(BH_, 10), 256, 0, stream>>>(qb, kb, rowmax, rowsum, pfx1, hist2);
  select_level<<<BH_, 64, 0, stream>>>(hist2, 4096, krem1, pfx1, krem2, pfx2, 12);
  hist_pass<2><<<dim3(BH_, 10), 256, 0, stream>>>(qb, kb, rowmax, rowsum, pfx2, hist3);
  select_level<<<BH_, 64, 0, stream>>>(hist3, 256, krem2, pfx2, krem3, sigb, 8);
  rank_kernel<<<B_, 576, 0, stream>>>(ldiag, rowmax, rowsum, sigb, kept);

  float* outp = (float*)d_out;
  gather_x<<<M2_, 256, 0, stream>>>(xo, kept, outp + (size_t)M2_ * C_);
  if (use_mfma_av)
    av_mfma<<<dim3(BH_, 9), 256, 0, stream>>>(qb, khi, klo, vthi, vtlo, kept,
                                              rowmax, rowsum, sigb, out1);
  else
    av_kernel<<<dim3(BH_, 9), 256, 0, stream>>>(qb, kb, vb, kept, rowmax, rowsum, sigb, out1);
  proj_mfma<<<dim3(65, 6), 256, 0, stream>>>(out1, pw, pb, outp);
}

// Round 12
// 1596.118 us; speedup vs baseline: 8.6067x; 1.0018x over previous
//
#include <hip/hip_runtime.h>
#include <cstdint>
#include <cstddef>

// Attention_41231686042092: ViT attention + softmax sparsification (per-(b,h)
// exact median threshold via 3-level radix select on f32 bit patterns) +
// diag-based token pruning + projection.
//
// Round-12: exact revert to round-10 (verified 1599us). Round-11's 3-way-split
// MFMA qkv flipped the token ranking (absmax 0.512) — measured proof that all
// passes upstream of the argsort must stay f32 with bit-exact chain order.
// MFMA remains only on the verified downstream kernels (av_mfma, proj_mfma).

namespace {
constexpr int B_  = 16;
constexpr int N_  = 577;
constexpr int C_  = 768;
constexpr int H_  = 12;
constexpr int HD_ = 64;
constexpr int BH_ = B_ * H_;            // 192
constexpr int KK_ = N_ - 57;            // 520 kept tokens
constexpr unsigned KIDX_ = 166464u;     // int(N*N*0.5), 0-based desc rank
constexpr int M1_ = B_ * N_;            // 9232
constexpr int M2_ = B_ * KK_;           // 8320
constexpr int NPAD_ = 640;              // padded n for bf16 planes
}

typedef __attribute__((ext_vector_type(8))) short bfx8;
typedef __attribute__((ext_vector_type(4))) float fx4;

__device__ __forceinline__ void fma4(const float4& a, const float4& b, float& acc) {
  acc = __builtin_fmaf(a.x, b.x, acc);
  acc = __builtin_fmaf(a.y, b.y, acc);
  acc = __builtin_fmaf(a.z, b.z, acc);
  acc = __builtin_fmaf(a.w, b.w, acc);
}

__device__ __forceinline__ unsigned short f2bf(float x) {
  unsigned u = __float_as_uint(x);
  unsigned r = u + 0x7FFFu + ((u >> 16) & 1u);
  return (unsigned short)(r >> 16);
}
__device__ __forceinline__ float bf2f(unsigned short h) {
  return __uint_as_float(((unsigned)h) << 16);
}

// ---------------------------------------------------------------- QKV GEMM
// Round-4 version: 64x128 tile, 4x8 microtile, k-chunk 64 (measured 526us).
__global__ __launch_bounds__(256) void qkv_gemm(
    const float* __restrict__ X, const float* __restrict__ W,
    float* __restrict__ qb, float* __restrict__ kb, float* __restrict__ vb) {
  __shared__ __align__(16) float Xs[64][68];
  __shared__ __align__(16) float Ws2[128][68];
  const int m0 = blockIdx.x * 64;
  const int n0 = blockIdx.y * 128;
  const int t = threadIdx.x;
  const int tx = t & 15, ty = t >> 4;
  float acc[4][8] = {};
  for (int k0 = 0; k0 < 768; k0 += 64) {
    __syncthreads();
    {
      const int c = t & 15, r0 = t >> 4;
#pragma unroll
      for (int s = 0; s < 4; s++) {
        int r = r0 + 16 * s;
        int gm = m0 + r;
        float4 v = make_float4(0.f, 0.f, 0.f, 0.f);
        if (gm < M1_) v = *(const float4*)&X[(size_t)gm * 768 + k0 + 4 * c];
        *(float4*)&Xs[r][4 * c] = v;
      }
#pragma unroll
      for (int s = 0; s < 8; s++) {
        int r = r0 + 16 * s;
        float4 v = *(const float4*)&W[(size_t)(n0 + r) * 768 + k0 + 4 * c];
        *(float4*)&Ws2[r][4 * c] = v;
      }
    }
    __syncthreads();
#pragma unroll 2
    for (int d4 = 0; d4 < 16; d4++) {
      float4 a4[4], b4[8];
#pragma unroll
      for (int i = 0; i < 4; i++) a4[i] = *(const float4*)&Xs[tx + 16 * i][4 * d4];
#pragma unroll
      for (int j = 0; j < 8; j++) b4[j] = *(const float4*)&Ws2[ty + 16 * j][4 * d4];
#pragma unroll
      for (int i = 0; i < 4; i++)
#pragma unroll
        for (int j = 0; j < 8; j++) fma4(a4[i], b4[j], acc[i][j]);
    }
  }
  for (int i = 0; i < 4; i++) {
    int gm = m0 + tx + 16 * i;
    if (gm >= M1_) continue;
    int b = gm / N_, n = gm % N_;
    for (int j = 0; j < 8; j++) {
      int gn = n0 + ty + 16 * j;
      int which = gn / C_, rem = gn % C_;
      int h = rem >> 6, d = rem & 63;
      float* dst = (which == 0) ? qb : (which == 1) ? kb : vb;
      dst[(((size_t)(b * H_ + h)) * N_ + n) * HD_ + d] = acc[i][j];
    }
  }
}

// ------------------------------------- K/V -> bf16 planes (for av_mfma)
__global__ __launch_bounds__(256) void cvt_planes(
    const float* __restrict__ kb, const float* __restrict__ vb,
    unsigned short* __restrict__ khi, unsigned short* __restrict__ klo,
    unsigned short* __restrict__ vthi, unsigned short* __restrict__ vtlo) {
  __shared__ __align__(16) float Vl[64][68];
  const int bh = blockIdx.x;
  const int n0 = blockIdx.y * 64;
  const int t = threadIdx.x;
  const int nl = t >> 2, c16 = (t & 3) * 16;
  const int gn = n0 + nl;
  {  // K planes (always write; zero beyond N_)
    short hh[16], ll[16];
    if (gn < N_) {
      const float* src = &kb[((size_t)bh * N_ + gn) * HD_ + c16];
#pragma unroll
      for (int u = 0; u < 16; u += 4) {
        float4 v = *(const float4*)&src[u];
        const float* vp = (const float*)&v;
#pragma unroll
        for (int e = 0; e < 4; e++) {
          unsigned short h = f2bf(vp[e]);
          hh[u + e] = (short)h;
          ll[u + e] = (short)f2bf(vp[e] - bf2f(h));
        }
      }
    } else {
#pragma unroll
      for (int e = 0; e < 16; e++) { hh[e] = 0; ll[e] = 0; }
    }
    unsigned short* kh = &khi[((size_t)bh * NPAD_ + gn) * HD_ + c16];
    unsigned short* kl = &klo[((size_t)bh * NPAD_ + gn) * HD_ + c16];
    *(bfx8*)&kh[0] = *(bfx8*)&hh[0]; *(bfx8*)&kh[8] = *(bfx8*)&hh[8];
    *(bfx8*)&kl[0] = *(bfx8*)&ll[0]; *(bfx8*)&kl[8] = *(bfx8*)&ll[8];
  }
  {  // V: stage f32 tile, then write transposed planes
    float4 z = make_float4(0.f, 0.f, 0.f, 0.f);
#pragma unroll
    for (int u = 0; u < 16; u += 4) {
      float4 v = z;
      if (gn < N_) v = *(const float4*)&vb[((size_t)bh * N_ + gn) * HD_ + c16 + u];
      *(float4*)&Vl[nl][c16 + u] = v;
    }
    __syncthreads();
    const int d = t >> 2, m16 = (t & 3) * 16;
    short hh[16], ll[16];
#pragma unroll
    for (int e = 0; e < 16; e++) {
      float x = Vl[m16 + e][d];
      unsigned short h = f2bf(x);
      hh[e] = (short)h;
      ll[e] = (short)f2bf(x - bf2f(h));
    }
    unsigned short* vh = &vthi[((size_t)bh * HD_ + d) * NPAD_ + n0 + m16];
    unsigned short* vl = &vtlo[((size_t)bh * HD_ + d) * NPAD_ + n0 + m16];
    *(bfx8*)&vh[0] = *(bfx8*)&hh[0]; *(bfx8*)&vh[8] = *(bfx8*)&hh[8];
    *(bfx8*)&vl[0] = *(bfx8*)&ll[0]; *(bfx8*)&vl[8] = *(bfx8*)&ll[8];
  }
}

// -------------------------------------------------- stats (QK pass #1)
// Round-8 exact code (68-col K staging; no spill).
__global__ __launch_bounds__(256) void attn_stats(
    const float* __restrict__ qb, const float* __restrict__ kb,
    float* __restrict__ rowmax_g, float* __restrict__ rowsum_g,
    float* __restrict__ ldiag) {
  __shared__ __align__(16) float Qs[64][68];
  __shared__ __align__(16) float Ksf[128][68];
  const int bh = blockIdx.x;
  const int q0 = blockIdx.y * 64;
  const int t = threadIdx.x;
  const int tx = t & 15, ty = t >> 4;
  {
    const int c = t & 15, r0 = t >> 4;
#pragma unroll
    for (int s = 0; s < 4; s++) {
      int r = r0 + 16 * s;
      int gq = q0 + r;
      float4 v = make_float4(0.f, 0.f, 0.f, 0.f);
      if (gq < N_) v = *(const float4*)&qb[((size_t)bh * N_ + gq) * HD_ + 4 * c];
      v.x *= 0.125f; v.y *= 0.125f; v.z *= 0.125f; v.w *= 0.125f;
      *(float4*)&Qs[r][4 * c] = v;
    }
  }
  float m[4], ss[4];
#pragma unroll
  for (int i = 0; i < 4; i++) { m[i] = -INFINITY; ss[i] = 0.f; }
  for (int n0 = 0; n0 < N_; n0 += 128) {
    __syncthreads();
    {
      const int c = t & 15, r0 = t >> 4;
#pragma unroll
      for (int s = 0; s < 8; s++) {
        int r = r0 + 16 * s;
        int gn = n0 + r;
        float4 v = make_float4(0.f, 0.f, 0.f, 0.f);
        if (gn < N_) v = *(const float4*)&kb[((size_t)bh * N_ + gn) * HD_ + 4 * c];
        *(float4*)&Ksf[r][4 * c] = v;
      }
    }
    __syncthreads();
    float l[4][8];
#pragma unroll
    for (int i = 0; i < 4; i++)
#pragma unroll
      for (int j = 0; j < 8; j++) l[i][j] = 0.f;
#pragma unroll 2
    for (int d4 = 0; d4 < 16; d4++) {
      float4 a4[4], b4[8];
#pragma unroll
      for (int i = 0; i < 4; i++) a4[i] = *(const float4*)&Qs[tx + 16 * i][4 * d4];
#pragma unroll
      for (int j = 0; j < 8; j++) b4[j] = *(const float4*)&Ksf[ty + 16 * j][4 * d4];
#pragma unroll
      for (int i = 0; i < 4; i++)
#pragma unroll
        for (int j = 0; j < 8; j++) fma4(a4[i], b4[j], l[i][j]);
    }
#pragma unroll
    for (int i = 0; i < 4; i++) {
      int gq = q0 + tx + 16 * i;
      float tmax = -INFINITY;
#pragma unroll
      for (int j = 0; j < 8; j++)
        if (n0 + ty + 16 * j < N_) tmax = fmaxf(tmax, l[i][j]);
      float mn = fmaxf(m[i], tmax);
      ss[i] *= expf(m[i] - mn);
#pragma unroll
      for (int j = 0; j < 8; j++) {
        int col = n0 + ty + 16 * j;
        if (col < N_) {
          ss[i] += expf(l[i][j] - mn);
          if (col == gq) ldiag[(size_t)bh * N_ + gq] = l[i][j];
        }
      }
      m[i] = mn;
    }
  }
  __syncthreads();
  float* Mred = &Ksf[0][0];   // overlay (Ksf dead): 64x16 each
  float* Sred = &Ksf[0][0] + 1024;
#pragma unroll
  for (int i = 0; i < 4; i++) {
    int row = tx + 16 * i;
    Mred[row * 16 + ty] = m[i];
    Sred[row * 16 + ty] = ss[i];
  }
  __syncthreads();
  if (t < 64) {
    int gq = q0 + t;
    if (gq < N_) {
      float M = -INFINITY;
      for (int k = 0; k < 16; k++) M = fmaxf(M, Mred[t * 16 + k]);
      float S = 0.f;
      for (int k = 0; k < 16; k++) S += expf(Mred[t * 16 + k] - M) * Sred[t * 16 + k];
      rowmax_g[(size_t)bh * N_ + gq] = M;
      rowsum_g[(size_t)bh * N_ + gq] = S;
    }
  }
}

// ----------------------------------------- histogram passes (QK #2,#3,#4)
// Round-8 exact code.
template <int MODE>
__global__ __launch_bounds__(256) void hist_pass(
    const float* __restrict__ qb, const float* __restrict__ kb,
    const float* __restrict__ rowmax_g, const float* __restrict__ rowsum_g,
    const unsigned* __restrict__ pfx_in, unsigned* __restrict__ hist_out) {
  constexpr int HB = (MODE == 2) ? 256 : 4096;
  __shared__ __align__(16) float Qs[64][68];
  __shared__ __align__(16) float Ksf[128][68];
  __shared__ unsigned hloc[HB];
  const int bh = blockIdx.x;
  const int q0 = blockIdx.y * 64;
  const int t = threadIdx.x;
  const int tx = t & 15, ty = t >> 4;
  for (int i = t; i < HB; i += 256) hloc[i] = 0u;
  const unsigned pf = (MODE == 0) ? 0u : pfx_in[bh];
  {
    const int c = t & 15, r0 = t >> 4;
#pragma unroll
    for (int s = 0; s < 4; s++) {
      int r = r0 + 16 * s;
      int gq = q0 + r;
      float4 v = make_float4(0.f, 0.f, 0.f, 0.f);
      if (gq < N_) v = *(const float4*)&qb[((size_t)bh * N_ + gq) * HD_ + 4 * c];
      v.x *= 0.125f; v.y *= 0.125f; v.z *= 0.125f; v.w *= 0.125f;
      *(float4*)&Qs[r][4 * c] = v;
    }
  }
  float M[4], inv[4];
#pragma unroll
  for (int i = 0; i < 4; i++) {
    int gq = q0 + tx + 16 * i;
    if (gq < N_) {
      M[i] = rowmax_g[(size_t)bh * N_ + gq];
      inv[i] = 1.f / rowsum_g[(size_t)bh * N_ + gq];
    } else { M[i] = 0.f; inv[i] = 0.f; }
  }
  for (int n0 = 0; n0 < N_; n0 += 128) {
    __syncthreads();
    {
      const int c = t & 15, r0 = t >> 4;
#pragma unroll
      for (int s = 0; s < 8; s++) {
        int r = r0 + 16 * s;
        int gn = n0 + r;
        float4 v = make_float4(0.f, 0.f, 0.f, 0.f);
        if (gn < N_) v = *(const float4*)&kb[((size_t)bh * N_ + gn) * HD_ + 4 * c];
        *(float4*)&Ksf[r][4 * c] = v;
      }
    }
    __syncthreads();
    float l[4][8];
#pragma unroll
    for (int i = 0; i < 4; i++)
#pragma unroll
      for (int j = 0; j < 8; j++) l[i][j] = 0.f;
#pragma unroll 2
    for (int d4 = 0; d4 < 16; d4++) {
      float4 a4[4], b4[8];
#pragma unroll
      for (int i = 0; i < 4; i++) a4[i] = *(const float4*)&Qs[tx + 16 * i][4 * d4];
#pragma unroll
      for (int j = 0; j < 8; j++) b4[j] = *(const float4*)&Ksf[ty + 16 * j][4 * d4];
#pragma unroll
      for (int i = 0; i < 4; i++)
#pragma unroll
        for (int j = 0; j < 8; j++) fma4(a4[i], b4[j], l[i][j]);
    }
#pragma unroll
    for (int i = 0; i < 4; i++) {
      int gq = q0 + tx + 16 * i;
#pragma unroll
      for (int j = 0; j < 8; j++) {
        bool valid = (gq < N_) && (n0 + ty + 16 * j < N_);
        if (MODE == 0) {
          unsigned bin = 0xFFFFu;
          if (valid) {
            float e = expf(l[i][j] - M[i]);
            float v = e * inv[i];
            bin = __float_as_uint(v) >> 20;
          }
          unsigned lead = (unsigned)__builtin_amdgcn_readfirstlane((int)bin);
          unsigned long long mm = __ballot(bin == lead);
          if (bin == lead) {
            if (lead != 0xFFFFu && (t & 63) == (__ffsll((unsigned long long)mm) - 1))
              atomicAdd(&hloc[lead], (unsigned)__popcll(mm));
          } else if (bin != 0xFFFFu) {
            atomicAdd(&hloc[bin], 1u);
          }
        } else if (valid) {
          float e = expf(l[i][j] - M[i]);
          float v = e * inv[i];
          unsigned bits = __float_as_uint(v);
          if (MODE == 1) {
            if ((bits >> 20) == pf) atomicAdd(&hloc[(bits >> 8) & 0xFFFu], 1u);
          } else {
            if ((bits >> 8) == pf) atomicAdd(&hloc[bits & 0xFFu], 1u);
          }
        }
      }
    }
  }
  __syncthreads();
  for (int i = t; i < HB; i += 256)
    if (hloc[i]) atomicAdd(&hist_out[(size_t)bh * HB + i], hloc[i]);
}

// ------------------------------------------------------ radix-select levels
__global__ __launch_bounds__(64) void select_level(
    const unsigned* __restrict__ hist, int nbins,
    const unsigned* __restrict__ krem_in, const unsigned* __restrict__ pfx_in,
    unsigned* __restrict__ krem_out, unsigned* __restrict__ pfx_out, int shift) {
  const int bh = blockIdx.x;
  const int l = threadIdx.x;
  const int seg = nbins / 64;
  const unsigned krem = krem_in ? krem_in[bh] : KIDX_;
  const unsigned* hb = hist + (size_t)bh * nbins;
  __shared__ unsigned ps[64];
  unsigned psum = 0;
  int hi = nbins - 1 - l * seg;
  for (int i = 0; i < seg; i++) psum += hb[hi - i];
  ps[l] = psum;
  __syncthreads();
  if (l == 0) {
    unsigned cum = 0, before = 0;
    int bin = 0;
    for (int j = 0; j < 64; j++) {
      if (cum + ps[j] > krem) {
        unsigned c = cum;
        int hj = nbins - 1 - j * seg;
        for (int i = 0; i < seg; i++) {
          unsigned cnt = hb[hj - i];
          if (c + cnt > krem) { bin = hj - i; before = c; break; }
          c += cnt;
        }
        break;
      }
      cum += ps[j];
    }
    unsigned p = pfx_in ? pfx_in[bh] : 0u;
    pfx_out[bh] = (p << shift) | (unsigned)bin;
    krem_out[bh] = krem - before;
  }
}

// ------------------------------------------------- token ranking (stable)
__global__ __launch_bounds__(576) void rank_kernel(
    const float* __restrict__ ldiag, const float* __restrict__ rowmax_g,
    const float* __restrict__ rowsum_g, const unsigned* __restrict__ sigbits,
    int* __restrict__ kept) {
  const int b = blockIdx.x;
  const int i = threadIdx.x;  // token i+1
  __shared__ float sc[576];
  float s = 0.f;
  for (int h = 0; h < H_; h++) {
    int bh = b * H_ + h;
    float l = ldiag[(size_t)bh * N_ + (i + 1)];
    float M = rowmax_g[(size_t)bh * N_ + (i + 1)];
    float inv = 1.f / rowsum_g[(size_t)bh * N_ + (i + 1)];
    float e = expf(l - M);
    float v = e * inv;   // bit-identical to hist computation
    float sg = __uint_as_float(sigbits[bh]);
    if (v >= sg) s = fmaxf(s, v);
  }
  sc[i] = s;
  __syncthreads();
  int r = 0;
  for (int j = 0; j < 576; j++) {
    float sj = sc[j];
    if (sj > s || (sj == s && j < i)) r++;
  }
  if (r < KK_ - 1) kept[b * KK_ + r + 1] = i + 1;
  if (i == 0) kept[b * KK_] = 0;
}

// ------------------------------------------------------ gather x_original
__global__ __launch_bounds__(256) void gather_x(
    const float* __restrict__ xo, const int* __restrict__ kept,
    float* __restrict__ out2) {
  const int bp = blockIdx.x;
  const int b = bp / KK_, p = bp % KK_;
  const int src = kept[b * KK_ + p];
  const float* s = xo + ((size_t)b * N_ + src) * C_;
  float* d = out2 + (size_t)bp * C_;
  for (int c = threadIdx.x; c < C_; c += 256) d[c] = s[c];
}

// --------------------------------- AV via bf16 MFMA (verified round-9/10)
__global__ __launch_bounds__(256) void av_mfma(
    const float* __restrict__ qb,
    const unsigned short* __restrict__ khi, const unsigned short* __restrict__ klo,
    const unsigned short* __restrict__ vthi, const unsigned short* __restrict__ vtlo,
    const int* __restrict__ kept, const float* __restrict__ rowmax_g,
    const float* __restrict__ rowsum_g, const unsigned* __restrict__ sigbits,
    float* __restrict__ out1) {
  __shared__ __align__(16) unsigned short Qh[64][72], Ql[64][72];
  __shared__ __align__(16) unsigned short Kh[64][72], Kl[64][72];  // -> P overlay
  __shared__ __align__(16) unsigned short Vh[64][72], Vlo[64][72]; // transposed V
  __shared__ int ridx[64];
  __shared__ float Ml[64], Il[64];
  const int bh = blockIdx.x;
  const int p0 = blockIdx.y * 64;
  const int b = bh / H_, h = bh % H_;
  const float sigma = __uint_as_float(sigbits[bh]);
  const int t = threadIdx.x;
  const int w = t >> 6, l = t & 63;
  const int lr = l & 15, lk8 = (l >> 4) * 8;
  if (t < 64) {
    int pp = p0 + t;
    int r = (pp < KK_) ? kept[b * KK_ + pp] : 0;
    ridx[t] = r;
    Ml[t] = rowmax_g[(size_t)bh * N_ + r];
    Il[t] = 1.f / rowsum_g[(size_t)bh * N_ + r];
  }
  __syncthreads();
  {  // stage Q planes (scaled by 0.125, exact pow2)
    const int qr = t >> 2, c16 = (t & 3) * 16;
    const float* src = &qb[((size_t)bh * N_ + ridx[qr]) * HD_ + c16];
    short hh[16], ll[16];
#pragma unroll
    for (int u = 0; u < 16; u += 4) {
      float4 v = *(const float4*)&src[u];
      const float* vp = (const float*)&v;
#pragma unroll
      for (int e = 0; e < 4; e++) {
        float x = vp[e] * 0.125f;
        unsigned short hb_ = f2bf(x);
        hh[u + e] = (short)hb_;
        ll[u + e] = (short)f2bf(x - bf2f(hb_));
      }
    }
    *(bfx8*)&Qh[qr][c16] = *(bfx8*)&hh[0]; *(bfx8*)&Qh[qr][c16 + 8] = *(bfx8*)&hh[8];
    *(bfx8*)&Ql[qr][c16] = *(bfx8*)&ll[0]; *(bfx8*)&Ql[qr][c16 + 8] = *(bfx8*)&ll[8];
  }
  fx4 accPV[4];
#pragma unroll
  for (int j = 0; j < 4; j++) accPV[j] = (fx4){0.f, 0.f, 0.f, 0.f};

  for (int n0 = 0; n0 < N_; n0 += 64) {
    __syncthreads();  // prev PV done (P overlays K)
    {  // stage K planes (rows n) and Vt planes (rows d)
      const int rr = t >> 2, c16 = (t & 3) * 16;
      const unsigned short* ksh = &khi[((size_t)bh * NPAD_ + n0 + rr) * HD_ + c16];
      const unsigned short* ksl = &klo[((size_t)bh * NPAD_ + n0 + rr) * HD_ + c16];
      *(bfx8*)&Kh[rr][c16] = *(const bfx8*)&ksh[0];
      *(bfx8*)&Kh[rr][c16 + 8] = *(const bfx8*)&ksh[8];
      *(bfx8*)&Kl[rr][c16] = *(const bfx8*)&ksl[0];
      *(bfx8*)&Kl[rr][c16 + 8] = *(const bfx8*)&ksl[8];
      const unsigned short* vsh = &vthi[((size_t)bh * HD_ + rr) * NPAD_ + n0 + c16];
      const unsigned short* vsl = &vtlo[((size_t)bh * HD_ + rr) * NPAD_ + n0 + c16];
      *(bfx8*)&Vh[rr][c16] = *(const bfx8*)&vsh[0];
      *(bfx8*)&Vh[rr][c16 + 8] = *(const bfx8*)&vsh[8];
      *(bfx8*)&Vlo[rr][c16] = *(const bfx8*)&vsl[0];
      *(bfx8*)&Vlo[rr][c16 + 8] = *(const bfx8*)&vsl[8];
    }
    __syncthreads();
    // QK: lacc[j] over 4 col-tiles
    bfx8 aH0 = *(const bfx8*)&Qh[16 * w + lr][lk8];
    bfx8 aH1 = *(const bfx8*)&Qh[16 * w + lr][32 + lk8];
    bfx8 aL0 = *(const bfx8*)&Ql[16 * w + lr][lk8];
    bfx8 aL1 = *(const bfx8*)&Ql[16 * w + lr][32 + lk8];
    fx4 lacc[4];
#pragma unroll
    for (int j = 0; j < 4; j++) {
      bfx8 bH0 = *(const bfx8*)&Kh[16 * j + lr][lk8];
      bfx8 bH1 = *(const bfx8*)&Kh[16 * j + lr][32 + lk8];
      bfx8 bL0 = *(const bfx8*)&Kl[16 * j + lr][lk8];
      bfx8 bL1 = *(const bfx8*)&Kl[16 * j + lr][32 + lk8];
      fx4 c = (fx4){0.f, 0.f, 0.f, 0.f};
      c = __builtin_amdgcn_mfma_f32_16x16x32_bf16(aH0, bH0, c, 0, 0, 0);
      c = __builtin_amdgcn_mfma_f32_16x16x32_bf16(aH1, bH1, c, 0, 0, 0);
      c = __builtin_amdgcn_mfma_f32_16x16x32_bf16(aH0, bL0, c, 0, 0, 0);
      c = __builtin_amdgcn_mfma_f32_16x16x32_bf16(aH1, bL1, c, 0, 0, 0);
      c = __builtin_amdgcn_mfma_f32_16x16x32_bf16(aL0, bH0, c, 0, 0, 0);
      c = __builtin_amdgcn_mfma_f32_16x16x32_bf16(aL1, bH1, c, 0, 0, 0);
      lacc[j] = c;
    }
    __syncthreads();  // all K reads done -> safe to overlay P
#pragma unroll
    for (int j = 0; j < 4; j++) {
#pragma unroll
      for (int r = 0; r < 4; r++) {
        int rr = 16 * w + (l >> 4) * 4 + r;
        int cc = 16 * j + lr;
        int gn = n0 + cc;
        float P = 0.f;
        if (gn < N_) {
          float e = expf(lacc[j][r] - Ml[rr]);
          float v = e * Il[rr];
          P = (v >= sigma) ? v : 0.f;
        }
        unsigned short ph = f2bf(P);
        Kh[rr][cc] = ph;
        Kl[rr][cc] = f2bf(P - bf2f(ph));
      }
    }
    __syncthreads();
    // PV
    bfx8 pH0 = *(const bfx8*)&Kh[16 * w + lr][lk8];
    bfx8 pH1 = *(const bfx8*)&Kh[16 * w + lr][32 + lk8];
    bfx8 pL0 = *(const bfx8*)&Kl[16 * w + lr][lk8];
    bfx8 pL1 = *(const bfx8*)&Kl[16 * w + lr][32 + lk8];
#pragma unroll
    for (int jd = 0; jd < 4; jd++) {
      bfx8 vH0 = *(const bfx8*)&Vh[16 * jd + lr][lk8];
      bfx8 vH1 = *(const bfx8*)&Vh[16 * jd + lr][32 + lk8];
      bfx8 vL0 = *(const bfx8*)&Vlo[16 * jd + lr][lk8];
      bfx8 vL1 = *(const bfx8*)&Vlo[16 * jd + lr][32 + lk8];
      fx4 c = accPV[jd];
      c = __builtin_amdgcn_mfma_f32_16x16x32_bf16(pH0, vH0, c, 0, 0, 0);
      c = __builtin_amdgcn_mfma_f32_16x16x32_bf16(pH1, vH1, c, 0, 0, 0);
      c = __builtin_amdgcn_mfma_f32_16x16x32_bf16(pH0, vL0, c, 0, 0, 0);
      c = __builtin_amdgcn_mfma_f32_16x16x32_bf16(pH1, vL1, c, 0, 0, 0);
      c = __builtin_amdgcn_mfma_f32_16x16x32_bf16(pL0, vH0, c, 0, 0, 0);
      c = __builtin_amdgcn_mfma_f32_16x16x32_bf16(pL1, vH1, c, 0, 0, 0);
      accPV[jd] = c;
    }
  }
#pragma unroll
  for (int jd = 0; jd < 4; jd++) {
#pragma unroll
    for (int r = 0; r < 4; r++) {
      int pp = p0 + 16 * w + (l >> 4) * 4 + r;
      if (pp < KK_)
        out1[((size_t)(b * KK_ + pp)) * C_ + h * HD_ + 16 * jd + lr] = accPV[jd][r];
    }
  }
}

// --------------------------------- AV fallback (f32, round-8 verified)
__global__ __launch_bounds__(256) void av_kernel(
    const float* __restrict__ qb, const float* __restrict__ kb,
    const float* __restrict__ vb, const int* __restrict__ kept,
    const float* __restrict__ rowmax_g, const float* __restrict__ rowsum_g,
    const unsigned* __restrict__ sigbits, float* __restrict__ out1) {
  __shared__ __align__(16) float Qs[64][68];
  __shared__ __align__(16) float Ksf[64][68];
  __shared__ __align__(16) float Vs[64][68];
  __shared__ int ridx[64];
  __shared__ float Ml[64], Il[64];
  const int bh = blockIdx.x;
  const int p0 = blockIdx.y * 64;
  const int b = bh / H_, h = bh % H_;
  const float sigma = __uint_as_float(sigbits[bh]);
  const int t = threadIdx.x;
  const int tx = t & 15, ty = t >> 4;
  if (t < 64) {
    int pp = p0 + t;
    int r = (pp < KK_) ? kept[b * KK_ + pp] : 0;
    ridx[t] = r;
    Ml[t] = rowmax_g[(size_t)bh * N_ + r];
    Il[t] = 1.f / rowsum_g[(size_t)bh * N_ + r];
  }
  __syncthreads();
  {
    const int c = t & 15, r0 = t >> 4;
#pragma unroll
    for (int s = 0; s < 4; s++) {
      int r = r0 + 16 * s;
      int gq = ridx[r];
      float4 v = *(const float4*)&qb[((size_t)bh * N_ + gq) * HD_ + 4 * c];
      v.x *= 0.125f; v.y *= 0.125f; v.z *= 0.125f; v.w *= 0.125f;
      *(float4*)&Qs[r][4 * c] = v;
    }
  }
  float M[4], inv[4];
#pragma unroll
  for (int i = 0; i < 4; i++) { int row = tx + 16 * i; M[i] = Ml[row]; inv[i] = Il[row]; }
  float acc[4][4] = {};
  for (int n0 = 0; n0 < N_; n0 += 64) {
    __syncthreads();
    {
      const int c = t & 15, r0 = t >> 4;
#pragma unroll
      for (int s = 0; s < 4; s++) {
        int r = r0 + 16 * s;
        int gn = n0 + r;
        float4 kv = make_float4(0.f, 0.f, 0.f, 0.f);
        float4 vv = make_float4(0.f, 0.f, 0.f, 0.f);
        if (gn < N_) {
          kv = *(const float4*)&kb[((size_t)bh * N_ + gn) * HD_ + 4 * c];
          vv = *(const float4*)&vb[((size_t)bh * N_ + gn) * HD_ + 4 * c];
        }
        *(float4*)&Ksf[r][4 * c] = kv;
        *(float4*)&Vs[r][4 * c] = vv;
      }
    }
    __syncthreads();
    float l[4][4];
#pragma unroll
    for (int i = 0; i < 4; i++)
#pragma unroll
      for (int j = 0; j < 4; j++) l[i][j] = 0.f;
#pragma unroll 4
    for (int d4 = 0; d4 < 16; d4++) {
      float4 a4[4], b4[4];
#pragma unroll
      for (int i = 0; i < 4; i++) a4[i] = *(const float4*)&Qs[tx + 16 * i][4 * d4];
#pragma unroll
      for (int j = 0; j < 4; j++) b4[j] = *(const float4*)&Ksf[4 * ty + j][4 * d4];
#pragma unroll
      for (int i = 0; i < 4; i++)
#pragma unroll
        for (int j = 0; j < 4; j++) fma4(a4[i], b4[j], l[i][j]);
    }
    __syncthreads();
#pragma unroll
    for (int i = 0; i < 4; i++) {
      float4 pv4;
      float* pp = (float*)&pv4;
#pragma unroll
      for (int j = 0; j < 4; j++) {
        float e = expf(l[i][j] - M[i]);
        float v = e * inv[i];
        pp[j] = (v >= sigma) ? v : 0.f;
      }
      *(float4*)&Ksf[tx + 16 * i][4 * ty] = pv4;
    }
    __syncthreads();
#pragma unroll 4
    for (int nb = 0; nb < 16; nb++) {
      float4 pa4[4];
#pragma unroll
      for (int i = 0; i < 4; i++) pa4[i] = *(const float4*)&Ksf[tx + 16 * i][4 * nb];
#pragma unroll
      for (int e = 0; e < 4; e++) {
        float4 vv4 = *(const float4*)&Vs[4 * nb + e][4 * ty];
#pragma unroll
        for (int i = 0; i < 4; i++) {
          float pvv = ((const float*)&pa4[i])[e];
          acc[i][0] = __builtin_fmaf(pvv, vv4.x, acc[i][0]);
          acc[i][1] = __builtin_fmaf(pvv, vv4.y, acc[i][1]);
          acc[i][2] = __builtin_fmaf(pvv, vv4.z, acc[i][2]);
          acc[i][3] = __builtin_fmaf(pvv, vv4.w, acc[i][3]);
        }
      }
    }
  }
#pragma unroll
  for (int i = 0; i < 4; i++) {
    int pp = p0 + tx + 16 * i;
    if (pp >= KK_) continue;
    float4 o = make_float4(acc[i][0], acc[i][1], acc[i][2], acc[i][3]);
    *(float4*)&out1[((size_t)(b * KK_ + pp)) * C_ + h * HD_ + 4 * ty] = o;
  }
}

// ------------------------------------------- proj GEMM via bf16 MFMA
__global__ __launch_bounds__(256) void proj_mfma(
    const float* __restrict__ Xi, const float* __restrict__ W,
    const float* __restrict__ bias, float* __restrict__ out) {
  __shared__ __align__(16) short XsH[128][40];
  __shared__ __align__(16) short XsL[128][40];
  __shared__ __align__(16) short WsH[128][40];
  __shared__ __align__(16) short WsL[128][40];
  const int m0 = blockIdx.x * 128;
  const int n0 = blockIdx.y * 128;
  const int t = threadIdx.x;
  const int w = t >> 6;
  const int l = t & 63;
  const int wm = (w & 1) * 64;
  const int wn = (w >> 1) * 64;
  const int srow = t >> 1;
  const int scol = (t & 1) * 16;

  fx4 acc[4][4];
#pragma unroll
  for (int i = 0; i < 4; i++)
#pragma unroll
    for (int j = 0; j < 4; j++) acc[i][j] = (fx4){0.f, 0.f, 0.f, 0.f};

  for (int k0 = 0; k0 < 768; k0 += 32) {
    __syncthreads();
    {
      const float* xsrc = &Xi[(size_t)(m0 + srow) * 768 + k0 + scol];
      const float* wsrc = &W[(size_t)(n0 + srow) * 768 + k0 + scol];
      short hx[16], lx[16], hw[16], lw[16];
#pragma unroll
      for (int u = 0; u < 16; u += 4) {
        float4 xv = *(const float4*)&xsrc[u];
        float4 wv = *(const float4*)&wsrc[u];
        const float* xp = (const float*)&xv;
        const float* wp = (const float*)&wv;
#pragma unroll
        for (int e = 0; e < 4; e++) {
          unsigned short h = f2bf(xp[e]);
          hx[u + e] = (short)h;
          lx[u + e] = (short)f2bf(xp[e] - bf2f(h));
          unsigned short g = f2bf(wp[e]);
          hw[u + e] = (short)g;
          lw[u + e] = (short)f2bf(wp[e] - bf2f(g));
        }
      }
      *(bfx8*)&XsH[srow][scol]     = *(bfx8*)&hx[0];
      *(bfx8*)&XsH[srow][scol + 8] = *(bfx8*)&hx[8];
      *(bfx8*)&XsL[srow][scol]     = *(bfx8*)&lx[0];
      *(bfx8*)&XsL[srow][scol + 8] = *(bfx8*)&lx[8];
      *(bfx8*)&WsH[srow][scol]     = *(bfx8*)&hw[0];
      *(bfx8*)&WsH[srow][scol + 8] = *(bfx8*)&hw[8];
      *(bfx8*)&WsL[srow][scol]     = *(bfx8*)&lw[0];
      *(bfx8*)&WsL[srow][scol + 8] = *(bfx8*)&lw[8];
    }
    __syncthreads();
    bfx8 aH[4], aL[4];
    const int ar = l & 15, ak = (l >> 4) * 8;
#pragma unroll
    for (int i = 0; i < 4; i++) {
      aH[i] = *(const bfx8*)&XsH[wm + 16 * i + ar][ak];
      aL[i] = *(const bfx8*)&XsL[wm + 16 * i + ar][ak];
    }
#pragma unroll
    for (int j = 0; j < 4; j++) {
      bfx8 bH = *(const bfx8*)&WsH[wn + 16 * j + ar][ak];
      bfx8 bL = *(const bfx8*)&WsL[wn + 16 * j + ar][ak];
#pragma unroll
      for (int i = 0; i < 4; i++) {
        acc[i][j] = __builtin_amdgcn_mfma_f32_16x16x32_bf16(aH[i], bH, acc[i][j], 0, 0, 0);
        acc[i][j] = __builtin_amdgcn_mfma_f32_16x16x32_bf16(aH[i], bL, acc[i][j], 0, 0, 0);
        acc[i][j] = __builtin_amdgcn_mfma_f32_16x16x32_bf16(aL[i], bH, acc[i][j], 0, 0, 0);
      }
    }
  }
  const int dc = l & 15, dr4 = (l >> 4) * 4;
#pragma unroll
  for (int j = 0; j < 4; j++) {
    int col = n0 + wn + 16 * j + dc;
    float bb = bias[col];
#pragma unroll
    for (int i = 0; i < 4; i++) {
#pragma unroll
      for (int r = 0; r < 4; r++) {
        int row = m0 + wm + 16 * i + dr4 + r;
        out[(size_t)row * C_ + col] = acc[i][j][r] + bb;
      }
    }
  }
}

// ---------------------------------------------------------------- launcher
extern "C" void kernel_launch(void* const* d_in, const int* in_sizes, int n_in,
                              void* d_out, int out_size, void* d_ws, size_t ws_size,
                              hipStream_t stream) {
  (void)in_sizes; (void)n_in; (void)out_size;
  const float* x    = (const float*)d_in[0];
  const float* xo   = (const float*)d_in[1];
  const float* qkvw = (const float*)d_in[2];
  const float* pw   = (const float*)d_in[3];
  const float* pb   = (const float*)d_in[4];

  char* ws = (char*)d_ws;
  size_t off = 0;
  auto alloc = [&](size_t bytes) -> char* {
    char* p = ws + off;
    off += (bytes + 255) & ~(size_t)255;
    return p;
  };
  const size_t szQ    = (size_t)BH_ * N_ * HD_ * 4;   // 28.4 MB
  const size_t szOut1 = (size_t)M2_ * C_ * 4;         // 25.6 MB
  const size_t szRow  = (size_t)BH_ * N_ * 4;
  const size_t szH12  = (size_t)BH_ * 4096 * 4;
  const size_t szH3   = (size_t)BH_ * 256 * 4;
  const size_t szPlane = (size_t)BH_ * NPAD_ * HD_ * 2;  // 15.7 MB each

  float* qb     = (float*)alloc(szQ);
  float* kb     = (float*)alloc(szQ);
  float* vb     = (float*)alloc(szQ);
  float* out1   = (float*)alloc(szOut1);
  float* ldiag  = (float*)alloc(szRow);
  float* rowmax = (float*)alloc(szRow);
  float* rowsum = (float*)alloc(szRow);
  unsigned* hist1 = (unsigned*)alloc(szH12);
  unsigned* hist2 = (unsigned*)alloc(szH12);
  unsigned* hist3 = (unsigned*)alloc(szH3);
  unsigned* pfx1  = (unsigned*)alloc(BH_ * 4);
  unsigned* krem1 = (unsigned*)alloc(BH_ * 4);
  unsigned* pfx2  = (unsigned*)alloc(BH_ * 4);
  unsigned* krem2 = (unsigned*)alloc(BH_ * 4);
  unsigned* sigb  = (unsigned*)alloc(BH_ * 4);
  unsigned* krem3 = (unsigned*)alloc(BH_ * 4);
  int* kept       = (int*)alloc((size_t)B_ * KK_ * 4);
  // bf16 planes last (optional, ws-guarded)
  unsigned short* khi  = (unsigned short*)alloc(szPlane);
  unsigned short* klo  = (unsigned short*)alloc(szPlane);
  unsigned short* vthi = (unsigned short*)alloc(szPlane);
  unsigned short* vtlo = (unsigned short*)alloc(szPlane);
  const bool use_mfma_av = (ws_size >= off);

  hipMemsetAsync(hist1, 0, szH12, stream);
  hipMemsetAsync(hist2, 0, szH12, stream);
  hipMemsetAsync(hist3, 0, szH3, stream);

  qkv_gemm<<<dim3(145, 18), 256, 0, stream>>>(x, qkvw, qb, kb, vb);
  if (use_mfma_av)
    cvt_planes<<<dim3(BH_, 10), 256, 0, stream>>>(kb, vb, khi, klo, vthi, vtlo);
  attn_stats<<<dim3(BH_, 10), 256, 0, stream>>>(qb, kb, rowmax, rowsum, ldiag);
  hist_pass<0><<<dim3(BH_, 10), 256, 0, stream>>>(qb, kb, rowmax, rowsum, nullptr, hist1);
  select_level<<<BH_, 64, 0, stream>>>(hist1, 4096, nullptr, nullptr, krem1, pfx1, 12);
  hist_pass<1><<<dim3(BH_, 10), 256, 0, stream>>>(qb, kb, rowmax, rowsum, pfx1, hist2);
  select_level<<<BH_, 64, 0, stream>>>(hist2, 4096, krem1, pfx1, krem2, pfx2, 12);
  hist_pass<2><<<dim3(BH_, 10), 256, 0, stream>>>(qb, kb, rowmax, rowsum, pfx2, hist3);
  select_level<<<BH_, 64, 0, stream>>>(hist3, 256, krem2, pfx2, krem3, sigb, 8);
  rank_kernel<<<B_, 576, 0, stream>>>(ldiag, rowmax, rowsum, sigb, kept);

  float* outp = (float*)d_out;
  gather_x<<<M2_, 256, 0, stream>>>(xo, kept, outp + (size_t)M2_ * C_);
  if (use_mfma_av)
    av_mfma<<<dim3(BH_, 9), 256, 0, stream>>>(qb, khi, klo, vthi, vtlo, kept,
                                              rowmax, rowsum, sigb, out1);
  else
    av_kernel<<<dim3(BH_, 9), 256, 0, stream>>>(qb, kb, vb, kept, rowmax, rowsum, sigb, out1);
  proj_mfma<<<dim3(65, 6), 256, 0, stream>>>(out1, pw, pb, outp);
}